// Round 7
// baseline (1571.505 us; speedup 1.0000x reference)
//
#include <hip/hip_runtime.h>
#include <math.h>

typedef _Float16 f16x8 __attribute__((ext_vector_type(8)));
typedef _Float16 f16x4 __attribute__((ext_vector_type(4)));
typedef float f32x4 __attribute__((ext_vector_type(4)));

#define TBM 128
#define TBN 128

// XCD-aware bijective swizzle of linear block id (nwg % 8 == 0 required for effect)
__device__ __forceinline__ int xcd_swz(int bid, int nwg)
{
    if ((nwg & 7) == 0) {
        int chunk = nwg >> 3;
        bid = (bid & 7) * chunk + (bid >> 3);
    }
    return bid;
}

// ---------------- direct-load f16 MFMA GEMM (no LDS, no barriers) ----------------
// v[m,n] = sum_k A[m,k]*B[n,k] + bias[n] ; K compile-time, 128x128 tile, 4 waves
// MODE 0: out = act(v) -> Yh f16 (or Yf fp32 if F32OUT); MODE 1: out = Yh + v (f16 RMW)
// ACT: 0 none, 1 leaky, 2 relu
template<int K, int MODE, int ACT, bool F32OUT>
__global__ __launch_bounds__(256)
void dgemm(const _Float16* __restrict__ A, const _Float16* __restrict__ B,
           const float* __restrict__ bias, _Float16* __restrict__ Yh,
           float* __restrict__ Yf, int M, int Nout)
{
    const int tid = threadIdx.x;
    const int lane = tid & 63;
    const int wid = tid >> 6;
    const int wr = wid >> 1, wc = wid & 1;

    int bid = xcd_swz(blockIdx.y * gridDim.x + blockIdx.x, gridDim.x * gridDim.y);
    const int m0 = (bid / gridDim.x) * TBM;
    const int n0 = (bid % gridDim.x) * TBN;

    const int fr = lane & 15;        // fragment row within 16
    const int ko = (lane >> 4) * 8;  // k offset (f16 elems)

    const _Float16* ap[4];
    const _Float16* bp[4];
#pragma unroll
    for (int mi = 0; mi < 4; mi++) {
        int am = min(m0 + wr * 64 + mi * 16 + fr, M - 1);
        ap[mi] = A + (size_t)am * K + ko;
    }
#pragma unroll
    for (int nj = 0; nj < 4; nj++) {
        int bn = min(n0 + wc * 64 + nj * 16 + fr, Nout - 1);
        bp[nj] = B + (size_t)bn * K + ko;
    }

    f32x4 acc[4][4] = {};
#pragma unroll 2
    for (int kk = 0; kk < K / 32; kk++) {
        f16x8 af[4], bf[4];
#pragma unroll
        for (int mi = 0; mi < 4; mi++) af[mi] = *(const f16x8*)(ap[mi] + kk * 32);
#pragma unroll
        for (int nj = 0; nj < 4; nj++) bf[nj] = *(const f16x8*)(bp[nj] + kk * 32);
#pragma unroll
        for (int mi = 0; mi < 4; mi++)
#pragma unroll
            for (int nj = 0; nj < 4; nj++)
                acc[mi][nj] = __builtin_amdgcn_mfma_f32_16x16x32_f16(af[mi], bf[nj], acc[mi][nj], 0, 0, 0);
    }

#pragma unroll
    for (int mi = 0; mi < 4; mi++) {
        int mbase = m0 + wr * 64 + mi * 16 + (lane >> 4) * 4;
#pragma unroll
        for (int nj = 0; nj < 4; nj++) {
            int n = n0 + wc * 64 + nj * 16 + (lane & 15);
            if (n < Nout) {
                float bv = bias ? bias[n] : 0.f;
#pragma unroll
                for (int r = 0; r < 4; r++) {
                    int m = mbase + r;
                    if (m < M) {
                        float v = acc[mi][nj][r] + bv;
                        size_t idx = (size_t)m * Nout + n;
                        if (MODE == 0) {
                            if (ACT == 1) v = v > 0.f ? v : 0.01f * v;
                            else if (ACT == 2) v = fmaxf(v, 0.f);
                            if (F32OUT) Yf[idx] = v;
                            else        Yh[idx] = (_Float16)v;
                        } else {
                            float s = (float)Yh[idx] + v;
                            Yh[idx] = (_Float16)s;
                        }
                    }
                }
            }
        }
    }
}

// ---------------- direct-load dual gate GEMM: Y = tanh(A@B1^T+c1) * sigmoid(A@B2^T+c2) ----------------
template<int K>
__global__ __launch_bounds__(256)
void dgat(const _Float16* __restrict__ A, const _Float16* __restrict__ B1,
          const _Float16* __restrict__ B2, const float* __restrict__ c1,
          const float* __restrict__ c2, _Float16* __restrict__ Y,
          int M, int Nout)
{
    const int tid = threadIdx.x;
    const int lane = tid & 63;
    const int wid = tid >> 6;
    const int wr = wid >> 1, wc = wid & 1;

    int bid = xcd_swz(blockIdx.y * gridDim.x + blockIdx.x, gridDim.x * gridDim.y);
    const int m0 = (bid / gridDim.x) * TBM;
    const int n0 = (bid % gridDim.x) * TBN;

    const int fr = lane & 15;
    const int ko = (lane >> 4) * 8;

    const _Float16* ap[4];
    const _Float16* b1p[4];
    const _Float16* b2p[4];
#pragma unroll
    for (int mi = 0; mi < 4; mi++) {
        int am = min(m0 + wr * 64 + mi * 16 + fr, M - 1);
        ap[mi] = A + (size_t)am * K + ko;
    }
#pragma unroll
    for (int nj = 0; nj < 4; nj++) {
        int bn = min(n0 + wc * 64 + nj * 16 + fr, Nout - 1);
        b1p[nj] = B1 + (size_t)bn * K + ko;
        b2p[nj] = B2 + (size_t)bn * K + ko;
    }

    f32x4 acc1[4][4] = {};
    f32x4 acc2[4][4] = {};
#pragma unroll 1
    for (int kk = 0; kk < K / 32; kk++) {
        f16x8 af[4], bf1[4], bf2[4];
#pragma unroll
        for (int mi = 0; mi < 4; mi++) af[mi] = *(const f16x8*)(ap[mi] + kk * 32);
#pragma unroll
        for (int nj = 0; nj < 4; nj++) {
            bf1[nj] = *(const f16x8*)(b1p[nj] + kk * 32);
            bf2[nj] = *(const f16x8*)(b2p[nj] + kk * 32);
        }
#pragma unroll
        for (int mi = 0; mi < 4; mi++)
#pragma unroll
            for (int nj = 0; nj < 4; nj++) {
                acc1[mi][nj] = __builtin_amdgcn_mfma_f32_16x16x32_f16(af[mi], bf1[nj], acc1[mi][nj], 0, 0, 0);
                acc2[mi][nj] = __builtin_amdgcn_mfma_f32_16x16x32_f16(af[mi], bf2[nj], acc2[mi][nj], 0, 0, 0);
            }
    }

#pragma unroll
    for (int mi = 0; mi < 4; mi++) {
        int mbase = m0 + wr * 64 + mi * 16 + (lane >> 4) * 4;
#pragma unroll
        for (int nj = 0; nj < 4; nj++) {
            int n = n0 + wc * 64 + nj * 16 + (lane & 15);
            if (n < Nout) {
                float bv1 = c1[n], bv2 = c2[n];
#pragma unroll
                for (int r = 0; r < 4; r++) {
                    int m = mbase + r;
                    if (m < M) {
                        float t1 = tanhf(acc1[mi][nj][r] + bv1);
                        float g1 = 1.f / (1.f + expf(-(acc2[mi][nj][r] + bv2)));
                        Y[(size_t)m * Nout + n] = (_Float16)(t1 * g1);
                    }
                }
            }
        }
    }
}

// ---------------- direct-load sim GEMM + fused row softmax (Kin <= 128) ----------------
// S = P@C^T ; sim = -sqrt(max(pp+cc-2S,1e-12))/denom ; Ah = softmax_row(sim) f16
template<int K>
__global__ __launch_bounds__(256)
void dsim(const _Float16* __restrict__ A, const _Float16* __restrict__ B,
          const float* __restrict__ Psq, const float* __restrict__ Csq,
          const float* __restrict__ sscale, _Float16* __restrict__ Ah,
          int M, int Kin)
{
    __shared__ float redmx[2][TBM];
    __shared__ float redsm[2][TBM];
    const int tid = threadIdx.x;
    const int lane = tid & 63;
    const int wid = tid >> 6;
    const int wr = wid >> 1, wc = wid & 1;
    const int m0 = blockIdx.y * TBM;

    const int fr = lane & 15;
    const int ko = (lane >> 4) * 8;

    const _Float16* ap[4];
    const _Float16* bp[4];
#pragma unroll
    for (int mi = 0; mi < 4; mi++) {
        int am = min(m0 + wr * 64 + mi * 16 + fr, M - 1);
        ap[mi] = A + (size_t)am * K + ko;
    }
#pragma unroll
    for (int nj = 0; nj < 4; nj++) {
        int bn = min(wc * 64 + nj * 16 + fr, Kin - 1);
        bp[nj] = B + (size_t)bn * K + ko;
    }

    f32x4 acc[4][4] = {};
#pragma unroll 2
    for (int kk = 0; kk < K / 32; kk++) {
        f16x8 af[4], bf[4];
#pragma unroll
        for (int mi = 0; mi < 4; mi++) af[mi] = *(const f16x8*)(ap[mi] + kk * 32);
#pragma unroll
        for (int nj = 0; nj < 4; nj++) bf[nj] = *(const f16x8*)(bp[nj] + kk * 32);
#pragma unroll
        for (int mi = 0; mi < 4; mi++)
#pragma unroll
            for (int nj = 0; nj < 4; nj++)
                acc[mi][nj] = __builtin_amdgcn_mfma_f32_16x16x32_f16(af[mi], bf[nj], acc[mi][nj], 0, 0, 0);
    }

    const float denom = fmaxf(1e-6f, sscale[0]);
    const int colbase = wc * 64 + (lane & 15);
    const int g = lane >> 4;
    float cc[4];
#pragma unroll
    for (int nj = 0; nj < 4; nj++) {
        int n = colbase + nj * 16;
        cc[nj] = (n < Kin) ? Csq[n] : 0.f;
    }

    // pass 1: sim values into acc, per-row max -> LDS
#pragma unroll
    for (int mi = 0; mi < 4; mi++) {
#pragma unroll
        for (int r = 0; r < 4; r++) {
            int row = wr * 64 + mi * 16 + g * 4 + r;
            float pp = Psq[m0 + row];
            float mx = -INFINITY;
#pragma unroll
            for (int nj = 0; nj < 4; nj++) {
                int n = colbase + nj * 16;
                float v = -INFINITY;
                if (n < Kin)
                    v = -sqrtf(fmaxf(pp + cc[nj] - 2.f * acc[mi][nj][r], 1e-12f)) / denom;
                acc[mi][nj][r] = v;
                mx = fmaxf(mx, v);
            }
#pragma unroll
            for (int o = 1; o < 16; o <<= 1) mx = fmaxf(mx, __shfl_xor(mx, o));
            if ((lane & 15) == 0) redmx[wc][row] = mx;
        }
    }
    __syncthreads();

    // pass 2: exp + per-row sum -> LDS
#pragma unroll
    for (int mi = 0; mi < 4; mi++) {
#pragma unroll
        for (int r = 0; r < 4; r++) {
            int row = wr * 64 + mi * 16 + g * 4 + r;
            float mx = fmaxf(redmx[0][row], redmx[1][row]);
            float s = 0.f;
#pragma unroll
            for (int nj = 0; nj < 4; nj++) {
                int n = colbase + nj * 16;
                float e = (n < Kin) ? expf(acc[mi][nj][r] - mx) : 0.f;
                acc[mi][nj][r] = e;
                s += e;
            }
#pragma unroll
            for (int o = 1; o < 16; o <<= 1) s += __shfl_xor(s, o);
            if ((lane & 15) == 0) redsm[wc][row] = s;
        }
    }
    __syncthreads();

    // pass 3: normalize + write f16
#pragma unroll
    for (int mi = 0; mi < 4; mi++) {
#pragma unroll
        for (int r = 0; r < 4; r++) {
            int row = wr * 64 + mi * 16 + g * 4 + r;
            float inv = 1.f / (redsm[0][row] + redsm[1][row]);
            int m = m0 + row;
#pragma unroll
            for (int nj = 0; nj < 4; nj++) {
                int n = colbase + nj * 16;
                if (n < Kin)
                    Ah[(size_t)m * Kin + n] = (_Float16)(acc[mi][nj][r] * inv);
            }
        }
    }
}

// ---------------- wave-per-output dot kernel (small-M fp32 GEMMs) ----------------
template<int ACT, bool F16OUT>
__global__ __launch_bounds__(256)
void dot_k(const float* __restrict__ X, const float* __restrict__ W,
           const float* __restrict__ bias, void* __restrict__ Yv,
           int M, int K)
{
    int gw = (blockIdx.x * 256 + threadIdx.x) >> 6;
    int lane = threadIdx.x & 63;
    if (gw >= M * 512) return;
    int r = gw >> 9, n = gw & 511;
    const float* xr = X + (size_t)r * K;
    const float* wr = W + (size_t)n * K;
    float d = 0.f;
    for (int t = 0; t < K; t += 256) {
        float4 a = *(const float4*)(xr + t + lane * 4);
        float4 b = *(const float4*)(wr + t + lane * 4);
        d += a.x * b.x + a.y * b.y + a.z * b.z + a.w * b.w;
    }
#pragma unroll
    for (int o = 32; o; o >>= 1) d += __shfl_xor(d, o);
    if (lane == 0) {
        float v = d + bias[n];
        if (ACT == 1) v = v > 0.f ? v : 0.01f * v;
        else if (ACT == 2) v = fmaxf(v, 0.f);
        if (F16OUT) ((_Float16*)Yv)[(size_t)r * 512 + n] = (_Float16)v;
        else        ((float*)Yv)[(size_t)r * 512 + n] = v;
    }
}

// ---------------- converters ----------------
__global__ __launch_bounds__(256)
void cvt_k(const float* __restrict__ x, _Float16* __restrict__ y, int n)
{
    int i = (blockIdx.x * 256 + threadIdx.x) * 4;
    if (i < n) {
        float4 v = *(const float4*)(x + i);
        f16x4 h = { (_Float16)v.x, (_Float16)v.y, (_Float16)v.z, (_Float16)v.w };
        *(f16x4*)(y + i) = h;
    }
}

// C [Kin,512] fp32 -> Ch [Kin,512] f16 and CTh [512,Kin] f16
__global__ __launch_bounds__(256)
void cvtC_k(const float* __restrict__ C, _Float16* __restrict__ Ch,
            _Float16* __restrict__ CTh, int Kin)
{
    int i = blockIdx.x * 256 + threadIdx.x;
    if (i < Kin * 512) {
        int j = i >> 9, d = i & 511;
        float v = C[i];
        Ch[i] = (_Float16)v;
        CTh[d * Kin + j] = (_Float16)v;
    }
}

// ---------------- small kernels (f16 activations) ----------------
__global__ __launch_bounds__(256)
void rowsq_k(const _Float16* __restrict__ X, float* __restrict__ out, int M)
{
    int wid = threadIdx.x >> 6, lane = threadIdx.x & 63;
    int row = blockIdx.x * 4 + wid;
    if (row >= M) return;
    f16x8 a = *(const f16x8*)(X + (size_t)row * 512 + lane * 8);
    float s = 0.f;
#pragma unroll
    for (int q = 0; q < 8; q++) { float f = (float)a[q]; s += f * f; }
#pragma unroll
    for (int o = 32; o; o >>= 1) s += __shfl_xor(s, o);
    if (lane == 0) out[row] = s;
}

// Yh = LN(X (+R)) * g + b, f16 in/out, fp32 math; one wave per row
__global__ __launch_bounds__(256)
void ln_k(const _Float16* __restrict__ X, const _Float16* __restrict__ R,
          const float* __restrict__ g, const float* __restrict__ b,
          _Float16* __restrict__ Yh, int M)
{
    int wid = threadIdx.x >> 6, lane = threadIdx.x & 63;
    int row = blockIdx.x * 4 + wid;
    if (row >= M) return;
    f16x8 a = *(const f16x8*)(X + (size_t)row * 512 + lane * 8);
    float v[8];
#pragma unroll
    for (int q = 0; q < 8; q++) v[q] = (float)a[q];
    if (R) {
        f16x8 c = *(const f16x8*)(R + (size_t)row * 512 + lane * 8);
#pragma unroll
        for (int q = 0; q < 8; q++) v[q] += (float)c[q];
    }
    float s = 0.f, ss = 0.f;
#pragma unroll
    for (int q = 0; q < 8; q++) { s += v[q]; ss += v[q] * v[q]; }
#pragma unroll
    for (int o = 32; o; o >>= 1) { s += __shfl_xor(s, o); ss += __shfl_xor(ss, o); }
    float mean = s * (1.f / 512.f);
    float var = ss * (1.f / 512.f) - mean * mean;
    float inv = 1.f / sqrtf(var + 1e-5f);
    int d0 = lane * 8;
    f16x8 o8;
#pragma unroll
    for (int q = 0; q < 8; q++)
        o8[q] = (_Float16)((v[q] - mean) * inv * g[d0 + q] + b[d0 + q]);
    *(f16x8*)(Yh + (size_t)row * 512 + d0) = o8;
}

__global__ __launch_bounds__(256)
void red1_k(const float* __restrict__ C, const float* __restrict__ w1,
            const float* __restrict__ b1, float* __restrict__ H1, int Kin)
{
    int d = blockIdx.x * 256 + threadIdx.x;
    int j = blockIdx.y;
    float acc = b1[j];
    for (int k = 0; k < Kin; k++) acc = fmaf(C[(size_t)k * 512 + d], w1[(size_t)j * Kin + k], acc);
    H1[(size_t)j * 512 + d] = fmaxf(acc, 0.f);
}

__global__ __launch_bounds__(256)
void red2_k(const float* __restrict__ H1, const float* __restrict__ w2,
            const float* __restrict__ b2, float* __restrict__ Cn, int Kin, int Kout)
{
    int d = blockIdx.x * 256 + threadIdx.x;
    int j2 = blockIdx.y;
    float acc = b2[j2];
    for (int j = 0; j < Kin; j++) acc = fmaf(H1[(size_t)j * 512 + d], w2[(size_t)j2 * Kin + j], acc);
    Cn[(size_t)j2 * 512 + d] = acc;
}

// scores[i] = dot(TG[i,:], Ws) + bs; TG f16
__global__ __launch_bounds__(256)
void score_k(const _Float16* __restrict__ TG, const float* __restrict__ Ws,
             const float* __restrict__ bs, float* __restrict__ out, int M)
{
    int wid = threadIdx.x >> 6, lane = threadIdx.x & 63;
    int row = blockIdx.x * 4 + wid;
    if (row >= M) return;
    f16x8 a = *(const f16x8*)(TG + (size_t)row * 512 + lane * 8);
    float4 w0 = *(const float4*)(Ws + lane * 8);
    float4 w1 = *(const float4*)(Ws + lane * 8 + 4);
    float d = (float)a[0] * w0.x + (float)a[1] * w0.y + (float)a[2] * w0.z + (float)a[3] * w0.w
            + (float)a[4] * w1.x + (float)a[5] * w1.y + (float)a[6] * w1.z + (float)a[7] * w1.w;
#pragma unroll
    for (int o = 32; o; o >>= 1) d += __shfl_xor(d, o);
    if (lane == 0) out[row] = d + bs[0];
}

__global__ __launch_bounds__(1024)
void pool_k(float* __restrict__ s, float* __restrict__ scal, int M)
{
    __shared__ float sm[16];
    int tid = threadIdx.x, lane = tid & 63, wid = tid >> 6;
    float mx = -INFINITY;
    for (int i = tid * 4; i < M; i += 4096) {
        float4 a = *(const float4*)(s + i);
        mx = fmaxf(fmaxf(fmaxf(mx, a.x), fmaxf(a.y, a.z)), a.w);
    }
#pragma unroll
    for (int o = 32; o; o >>= 1) mx = fmaxf(mx, __shfl_xor(mx, o));
    if (lane == 0) sm[wid] = mx;
    __syncthreads();
    if (wid == 0) {
        float v = (lane < 16) ? sm[lane] : -INFINITY;
#pragma unroll
        for (int o = 8; o; o >>= 1) v = fmaxf(v, __shfl_xor(v, o));
        if (lane == 0) sm[0] = v;
    }
    __syncthreads();
    float gmax = sm[0];
    __syncthreads();
    float sum = 0.f;
    for (int i = tid * 4; i < M; i += 4096) {
        float4 a = *(const float4*)(s + i);
        float4 e;
        e.x = expf(a.x - gmax); e.y = expf(a.y - gmax);
        e.z = expf(a.z - gmax); e.w = expf(a.w - gmax);
        *(float4*)(s + i) = e;
        sum += e.x + e.y + e.z + e.w;
    }
#pragma unroll
    for (int o = 32; o; o >>= 1) sum += __shfl_xor(sum, o);
    if (lane == 0) sm[wid] = sum;
    __syncthreads();
    if (tid == 0) {
        float t = 0.f;
        for (int w = 0; w < 16; w++) t += sm[w];
        scal[0] = t;
    }
}

__global__ __launch_bounds__(256)
void bagp_k(const _Float16* __restrict__ Z, const float* __restrict__ w,
            float* __restrict__ PB, int M, int cs)
{
    int d = blockIdx.x * 256 + threadIdx.x;
    int chunk = blockIdx.y;
    int i0 = chunk * cs;
    int i1 = min(M, i0 + cs);
    float acc = 0.f;
    for (int i = i0; i < i1; i++) acc = fmaf(w[i], (float)Z[(size_t)i * 512 + d], acc);
    PB[(size_t)chunk * 512 + d] = acc;
}

__global__ __launch_bounds__(256)
void bagf_k(const float* __restrict__ PB, const float* __restrict__ scal,
            float* __restrict__ bag, int nchunk)
{
    int d = blockIdx.x * 256 + threadIdx.x;
    float acc = 0.f;
    for (int c = 0; c < nchunk; c++) acc += PB[(size_t)c * 512 + d];
    bag[d] = acc / scal[0];
}

__global__ __launch_bounds__(256)
void h_k(const float* __restrict__ bag, const float* __restrict__ Wh,
         const float* __restrict__ bh, float* __restrict__ h)
{
    int wid = threadIdx.x >> 6, lane = threadIdx.x & 63;
    int j = blockIdx.x * 4 + wid;
    const float* wr = Wh + (size_t)j * 512;
    float d = 0.f;
#pragma unroll
    for (int t = 0; t < 2; t++) {
        float4 a = *(const float4*)(wr + t * 256 + lane * 4);
        float4 bv = *(const float4*)(bag + t * 256 + lane * 4);
        d += a.x * bv.x + a.y * bv.y + a.z * bv.z + a.w * bv.w;
    }
#pragma unroll
    for (int o = 32; o; o >>= 1) d += __shfl_xor(d, o);
    if (lane == 0) h[j] = fmaxf(d + bh[j], 0.f);
}

__global__ __launch_bounds__(128)
void logit_k(const float* __restrict__ h, const float* __restrict__ Wc,
             const float* __restrict__ bc, float* __restrict__ out)
{
    int wid = threadIdx.x >> 6, lane = threadIdx.x & 63;
    const float* wr = Wc + (size_t)wid * 512;
    float d = 0.f;
#pragma unroll
    for (int t = 0; t < 2; t++) {
        float4 a = *(const float4*)(wr + t * 256 + lane * 4);
        float4 hv = *(const float4*)(h + t * 256 + lane * 4);
        d += a.x * hv.x + a.y * hv.y + a.z * hv.z + a.w * hv.w;
    }
#pragma unroll
    for (int o = 32; o; o >>= 1) d += __shfl_xor(d, o);
    if (lane == 0) out[wid] = d + bc[wid];
}

extern "C" void kernel_launch(void* const* d_in, const int* in_sizes, int n_in,
                              void* d_out, int out_size, void* d_ws, size_t ws_size,
                              hipStream_t stream)
{
    const float* data    = (const float*)d_in[0];
    const float* protos  = (const float*)d_in[1];
    const float* W_pp    = (const float*)d_in[2];
    const float* b_pp    = (const float*)d_in[3];
    const float* W_cp    = (const float*)d_in[4];
    const float* b_cp    = (const float*)d_in[5];
    const float* sscale  = (const float*)d_in[6];
    const float* enh_w1  = (const float*)d_in[7];
    const float* enh_b1  = (const float*)d_in[8];
    const float* enh_w2  = (const float*)d_in[9];
    const float* enh_b2  = (const float*)d_in[10];
    const float* ln_g    = (const float*)d_in[11];
    const float* ln_b    = (const float*)d_in[12];
    const float* red_w1[3] = {(const float*)d_in[13], (const float*)d_in[17], (const float*)d_in[21]};
    const float* red_b1[3] = {(const float*)d_in[14], (const float*)d_in[18], (const float*)d_in[22]};
    const float* red_w2[3] = {(const float*)d_in[15], (const float*)d_in[19], (const float*)d_in[23]};
    const float* red_b2[3] = {(const float*)d_in[16], (const float*)d_in[20], (const float*)d_in[24]};
    const float* W_proc  = (const float*)d_in[25];
    const float* b_proc  = (const float*)d_in[26];
    const float* g_an    = (const float*)d_in[27];
    const float* b_an    = (const float*)d_in[28];
    const float* W_t     = (const float*)d_in[29];
    const float* b_t     = (const float*)d_in[30];
    const float* W_g     = (const float*)d_in[31];
    const float* b_g     = (const float*)d_in[32];
    const float* W_s     = (const float*)d_in[33];
    const float* b_s     = (const float*)d_in[34];
    const float* W_h     = (const float*)d_in[35];
    const float* b_h     = (const float*)d_in[36];
    const float* W_c     = (const float*)d_in[37];
    const float* b_c     = (const float*)d_in[38];
    float* out = (float*)d_out;

    constexpr int N = 32768, DIN = 768, D = 512;
    constexpr int NCHUNK = 256;
    char* w = (char*)d_ws;
    auto alloc = [&](size_t bytes) -> char* {
        char* p = w; w += (bytes + 255) & ~(size_t)255; return p;
    };
    _Float16* Ph     = (_Float16*)alloc((size_t)N * D * 2);
    _Float16* CTXh   = (_Float16*)alloc((size_t)N * D * 2);
    _Float16* TMPh   = (_Float16*)alloc((size_t)N * D * 2);
    _Float16* Zrawh  = (_Float16*)alloc((size_t)(N + 16) * D * 2);
    _Float16* Zh     = (_Float16*)alloc((size_t)(N + 16) * D * 2);
    _Float16* TGh    = (_Float16*)alloc((size_t)(N + 16) * D * 2);
    _Float16* datah  = (_Float16*)alloc((size_t)N * DIN * 2);
    _Float16* Ah     = (_Float16*)alloc((size_t)N * 128 * 2);
    _Float16* Ch     = (_Float16*)alloc(128 * D * 2);
    _Float16* CTh    = (_Float16*)alloc(128 * D * 2);
    _Float16* Wpph   = (_Float16*)alloc((size_t)D * DIN * 2);
    _Float16* w1h    = (_Float16*)alloc((size_t)3 * D * D * 2);
    _Float16* w2h    = (_Float16*)alloc((size_t)3 * D * D * 2);
    _Float16* Wproch = (_Float16*)alloc((size_t)D * D * 2);
    _Float16* Wth    = (_Float16*)alloc((size_t)D * D * 2);
    _Float16* Wgh    = (_Float16*)alloc((size_t)D * D * 2);
    float*    Psq    = (float*)alloc((size_t)N * 4);
    float*    Csq    = (float*)alloc(128 * 4);
    float*    Ca     = (float*)alloc(128 * D * 4);
    float*    Cb     = (float*)alloc(128 * D * 4);
    float*    H1     = (float*)alloc(128 * D * 4);
    float*    scr    = (float*)alloc((size_t)(N + 16) * 4);
    float*    PB     = (float*)alloc((size_t)NCHUNK * D * 4);
    float*    bag    = (float*)alloc(D * 4);
    float*    hb     = (float*)alloc(D * 4);
    float*    scal   = (float*)alloc(8 * 4);

    dim3 blk(256);
    auto cgrid = [](size_t n) { return dim3((unsigned)((n / 4 + 255) / 256)); };
    auto mgrid = [](int M_, int Nout_) { return dim3((Nout_ + TBN - 1) / TBN, (M_ + TBM - 1) / TBM); };

    // --- convert weights + data to f16 ---
    cvt_k<<<cgrid((size_t)N * DIN), blk, 0, stream>>>(data, datah, N * DIN);
    cvt_k<<<cgrid((size_t)D * DIN), blk, 0, stream>>>(W_pp, Wpph, D * DIN);
    cvt_k<<<cgrid((size_t)3 * D * D), blk, 0, stream>>>(enh_w1, w1h, 3 * D * D);
    cvt_k<<<cgrid((size_t)3 * D * D), blk, 0, stream>>>(enh_w2, w2h, 3 * D * D);
    cvt_k<<<cgrid((size_t)D * D), blk, 0, stream>>>(W_proc, Wproch, D * D);
    cvt_k<<<cgrid((size_t)D * D), blk, 0, stream>>>(W_t, Wth, D * D);
    cvt_k<<<cgrid((size_t)D * D), blk, 0, stream>>>(W_g, Wgh, D * D);

    // P = leaky(data @ W_pp^T + b_pp) -> f16
    dgemm<768, 0, 1, false><<<mgrid(N, D), blk, 0, stream>>>(datah, Wpph, b_pp, Ph, nullptr, N, D);
    // C0 = leaky(protos @ W_cp^T + b_cp) -> fp32 (tiny)
    dot_k<1, false><<<dim3(128 * 512 / 4), blk, 0, stream>>>(protos, W_cp, b_cp, Ca, 128, DIN);

    float* C = Ca;
    float* Cn = Cb;
    int Kin = 128;
    for (int i = 0; i < 3; i++) {
        int Kout = Kin >> 1;
        rowsq_k<<<dim3((N + 3) / 4), blk, 0, stream>>>(Ph, Psq, N);
        cvtC_k<<<dim3((Kin * D + 255) / 256), blk, 0, stream>>>(C, Ch, CTh, Kin);
        rowsq_k<<<dim3((Kin + 3) / 4), blk, 0, stream>>>(Ch, Csq, Kin);
        // A = softmax(-dist/denom) fused with S = P@C^T
        dsim<512><<<dim3(1, N / TBM), blk, 0, stream>>>(Ph, Ch, Psq, Csq, sscale, Ah, N, Kin);
        // ctx = A @ C -> f16
        if (Kin == 128)
            dgemm<128, 0, 0, false><<<mgrid(N, D), blk, 0, stream>>>(Ah, CTh, nullptr, CTXh, nullptr, N, D);
        else if (Kin == 64)
            dgemm<64, 0, 0, false><<<mgrid(N, D), blk, 0, stream>>>(Ah, CTh, nullptr, CTXh, nullptr, N, D);
        else
            dgemm<32, 0, 0, false><<<mgrid(N, D), blk, 0, stream>>>(Ah, CTh, nullptr, CTXh, nullptr, N, D);
        // P = LN(P + ctx) -> f16
        ln_k<<<dim3((N + 3) / 4), blk, 0, stream>>>(Ph, CTXh, ln_g + (size_t)i * D, ln_b + (size_t)i * D, Ph, N);
        // enhancer MLP: P += w2 @ relu(w1 @ P + b1) + b2
        dgemm<512, 0, 2, false><<<mgrid(N, D), blk, 0, stream>>>(Ph, w1h + (size_t)i * D * D, enh_b1 + (size_t)i * D, TMPh, nullptr, N, D);
        dgemm<512, 1, 0, false><<<mgrid(N, D), blk, 0, stream>>>(TMPh, w2h + (size_t)i * D * D, enh_b2 + (size_t)i * D, Ph, nullptr, N, D);
        // ProtoReducer (fp32, tiny)
        red1_k<<<dim3(2, Kin), blk, 0, stream>>>(C, red_w1[i], red_b1[i], H1, Kin);
        red2_k<<<dim3(2, Kout), blk, 0, stream>>>(H1, red_w2[i], red_b2[i], Cn, Kin, Kout);
        float* t = C; C = Cn; Cn = t;
        Kin = Kout;
    }

    // Zraw = relu(proc([P; C]))
    dgemm<512, 0, 2, false><<<mgrid(N, D), blk, 0, stream>>>(Ph, Wproch, b_proc, Zrawh, nullptr, N, D);
    dot_k<2, true><<<dim3(16 * 512 / 4), blk, 0, stream>>>(C, W_proc, b_proc, Zrawh + (size_t)N * D, 16, D);
    // Z = LN(Zraw)
    ln_k<<<dim3((N + 16 + 3) / 4), blk, 0, stream>>>(Zrawh, nullptr, g_an, b_an, Zh, N + 16);

    // TG = tanh(Z@W_t^T+b_t) * sigmoid(Z@W_g^T+b_g)  (fused dual GEMM, direct loads)
    dgat<512><<<mgrid(N + 16, D), blk, 0, stream>>>(Zh, Wth, Wgh, b_t, b_g, TGh, N + 16, D);

    // attention pooling
    score_k<<<dim3((N + 16 + 3) / 4), blk, 0, stream>>>(TGh, W_s, b_s, scr, N + 16);
    pool_k<<<dim3(1), dim3(1024), 0, stream>>>(scr, scal, N + 16);
    int cs = (N + 16 + NCHUNK - 1) / NCHUNK;
    bagp_k<<<dim3(2, NCHUNK), blk, 0, stream>>>(Zh, scr, PB, N + 16, cs);
    bagf_k<<<dim3(2), blk, 0, stream>>>(PB, scal, bag, NCHUNK);

    // classifier head
    h_k<<<dim3(128), blk, 0, stream>>>(bag, W_h, b_h, hb);
    logit_k<<<dim3(1), dim3(128), 0, stream>>>(hb, W_c, b_c, out);
}

// Round 8
// 1145.353 us; speedup vs baseline: 1.3721x; 1.3721x over previous
//
#include <hip/hip_runtime.h>
#include <math.h>

typedef _Float16 f16x8 __attribute__((ext_vector_type(8)));
typedef _Float16 f16x4 __attribute__((ext_vector_type(4)));
typedef float f32x4 __attribute__((ext_vector_type(4)));

#define TBM 128
#define TBN 128
#define TBK 32

#define AS1 __attribute__((address_space(1)))
#define AS3 __attribute__((address_space(3)))

__device__ __forceinline__ void gll16(const _Float16* g, _Float16* l)
{
    // direct global->LDS, 16B per lane; LDS dest = wave-uniform base + lane*16
    __builtin_amdgcn_global_load_lds((const AS1 unsigned int*)g,
                                     (AS3 unsigned int*)l, 16, 0, 0);
}

// XCD-aware bijective swizzle of linear block id (nwg % 8 == 0 required for effect)
__device__ __forceinline__ int xcd_swz(int bid, int nwg)
{
    if ((nwg & 7) == 0) {
        int chunk = nwg >> 3;
        bid = (bid & 7) * chunk + (bid >> 3);
    }
    return bid;
}

// ---------------- wave-per-output dot kernel (small-M fp32 GEMMs) ----------------
// ACT: 1 leaky, 2 relu ; F16OUT selects output dtype
template<int ACT, bool F16OUT>
__global__ __launch_bounds__(256)
void dot_k(const float* __restrict__ X, const float* __restrict__ W,
           const float* __restrict__ bias, void* __restrict__ Yv,
           int M, int K)
{
    int gw = (blockIdx.x * 256 + threadIdx.x) >> 6;
    int lane = threadIdx.x & 63;
    if (gw >= M * 512) return;
    int r = gw >> 9, n = gw & 511;
    const float* xr = X + (size_t)r * K;
    const float* wr = W + (size_t)n * K;
    float d = 0.f;
    for (int t = 0; t < K; t += 256) {
        float4 a = *(const float4*)(xr + t + lane * 4);
        float4 b = *(const float4*)(wr + t + lane * 4);
        d += a.x * b.x + a.y * b.y + a.z * b.z + a.w * b.w;
    }
#pragma unroll
    for (int o = 32; o; o >>= 1) d += __shfl_xor(d, o);
    if (lane == 0) {
        float v = d + bias[n];
        if (ACT == 1) v = v > 0.f ? v : 0.01f * v;
        else if (ACT == 2) v = fmaxf(v, 0.f);
        if (F16OUT) ((_Float16*)Yv)[(size_t)r * 512 + n] = (_Float16)v;
        else        ((float*)Yv)[(size_t)r * 512 + n] = v;
    }
}

// ---------------- f16 MFMA GEMM: 3-buffer LDS pipeline, counted vmcnt, raw barrier ----------------
// v[m,n] = sum_k A[m,k]*B[n,k] + bias[n]
// MODE 0: out = act(v) -> Yh f16 (or Yf fp32 if F32OUT); MODE 1: out = Yh + v
// ACT: 0 none, 1 leaky, 2 relu
template<int MODE, int ACT, bool F32OUT>
__global__ __launch_bounds__(256)
void mgemm(const _Float16* __restrict__ A, const _Float16* __restrict__ B,
           const float* __restrict__ bias, _Float16* __restrict__ Yh,
           float* __restrict__ Yf, int M, int K, int Nout)
{
    __shared__ _Float16 As[3][TBM * TBK];
    __shared__ _Float16 Bs[3][TBM * TBK];
    const int tid = threadIdx.x;
    const int lane = tid & 63;
    const int wid = tid >> 6;
    const int wr = wid >> 1, wc = wid & 1;

    int bid = xcd_swz(blockIdx.y * gridDim.x + blockIdx.x, gridDim.x * gridDim.y);
    const int m0 = (bid / gridDim.x) * TBM;
    const int n0 = (bid % gridDim.x) * TBN;

    f32x4 acc[4][4] = {};
    const int nt = K / TBK;

    const int lrow = lane >> 2;          // 0..15 row within chunk
    const int lk = (lane & 3) * 8;       // f16 offset within 32-elem k slab

    auto stage = [&](int t, int buf) {   // 4 gll per wave
        const int k0 = t * TBK;
#pragma unroll
        for (int q = 0; q < 2; q++) {
            int c = wid * 2 + q;                      // 0..7
            int r = c * 16 + lrow;
            int am = min(m0 + r, M - 1);
            int bn = min(n0 + r, Nout - 1);
            gll16(A + (size_t)am * K + k0 + lk, &As[buf][c * 512]);
            gll16(B + (size_t)bn * K + k0 + lk, &Bs[buf][c * 512]);
        }
    };

    stage(0, 0);
    if (nt > 1) stage(1, 1);
    for (int t = 0; t < nt; ++t) {
        if (t + 1 < nt) asm volatile("s_waitcnt vmcnt(4)");
        else            asm volatile("s_waitcnt vmcnt(0)");
        __builtin_amdgcn_s_barrier();                 // tile t resident for all waves
        if (t + 2 < nt) stage(t + 2, (t + 2) % 3);    // overwrites buf freed at iter t-1
        const int cur = t % 3;
        f16x8 af[4], bf[4];
#pragma unroll
        for (int mi = 0; mi < 4; mi++)
            af[mi] = *(const f16x8*)(&As[cur][(wr * 64 + mi * 16 + (lane & 15)) * TBK + (lane >> 4) * 8]);
#pragma unroll
        for (int nj = 0; nj < 4; nj++)
            bf[nj] = *(const f16x8*)(&Bs[cur][(wc * 64 + nj * 16 + (lane & 15)) * TBK + (lane >> 4) * 8]);
#pragma unroll
        for (int mi = 0; mi < 4; mi++)
#pragma unroll
            for (int nj = 0; nj < 4; nj++)
                acc[mi][nj] = __builtin_amdgcn_mfma_f32_16x16x32_f16(af[mi], bf[nj], acc[mi][nj], 0, 0, 0);
    }

#pragma unroll
    for (int mi = 0; mi < 4; mi++) {
        int mbase = m0 + wr * 64 + mi * 16 + (lane >> 4) * 4;
#pragma unroll
        for (int nj = 0; nj < 4; nj++) {
            int n = n0 + wc * 64 + nj * 16 + (lane & 15);
            if (n < Nout) {
                float bv = bias ? bias[n] : 0.f;
#pragma unroll
                for (int r = 0; r < 4; r++) {
                    int m = mbase + r;
                    if (m < M) {
                        float v = acc[mi][nj][r] + bv;
                        size_t idx = (size_t)m * Nout + n;
                        if (MODE == 0) {
                            if (ACT == 1) v = v > 0.f ? v : 0.01f * v;
                            else if (ACT == 2) v = fmaxf(v, 0.f);
                            if (F32OUT) Yf[idx] = v;
                            else        Yh[idx] = (_Float16)v;
                        } else {
                            float s = (float)Yh[idx] + v;
                            Yh[idx] = (_Float16)s;
                        }
                    }
                }
            }
        }
    }
}

// ---------------- fused dual gate GEMM: Y = tanh(A@B1^T+c1)*sigmoid(A@B2^T+c2), 3-buf pipeline ----------------
__global__ __launch_bounds__(256)
void gatgemm(const _Float16* __restrict__ A, const _Float16* __restrict__ B1,
             const _Float16* __restrict__ B2, const float* __restrict__ c1,
             const float* __restrict__ c2, _Float16* __restrict__ Y,
             int M, int K, int Nout)
{
    __shared__ _Float16 As[3][TBM * TBK];
    __shared__ _Float16 B1s[3][TBM * TBK];
    __shared__ _Float16 B2s[3][TBM * TBK];
    const int tid = threadIdx.x;
    const int lane = tid & 63;
    const int wid = tid >> 6;
    const int wr = wid >> 1, wc = wid & 1;

    int bid = xcd_swz(blockIdx.y * gridDim.x + blockIdx.x, gridDim.x * gridDim.y);
    const int m0 = (bid / gridDim.x) * TBM;
    const int n0 = (bid % gridDim.x) * TBN;

    f32x4 acc1[4][4] = {};
    f32x4 acc2[4][4] = {};
    const int nt = K / TBK;

    const int lrow = lane >> 2;
    const int lk = (lane & 3) * 8;

    auto stage = [&](int t, int buf) {   // 6 gll per wave
        const int k0 = t * TBK;
#pragma unroll
        for (int q = 0; q < 2; q++) {
            int c = wid * 2 + q;
            int r = c * 16 + lrow;
            int am = min(m0 + r, M - 1);
            int bn = min(n0 + r, Nout - 1);
            gll16(A + (size_t)am * K + k0 + lk, &As[buf][c * 512]);
            gll16(B1 + (size_t)bn * K + k0 + lk, &B1s[buf][c * 512]);
            gll16(B2 + (size_t)bn * K + k0 + lk, &B2s[buf][c * 512]);
        }
    };

    stage(0, 0);
    if (nt > 1) stage(1, 1);
    for (int t = 0; t < nt; ++t) {
        if (t + 1 < nt) asm volatile("s_waitcnt vmcnt(6)");
        else            asm volatile("s_waitcnt vmcnt(0)");
        __builtin_amdgcn_s_barrier();
        if (t + 2 < nt) stage(t + 2, (t + 2) % 3);
        const int cur = t % 3;
        f16x8 af[4], bf1[4], bf2[4];
#pragma unroll
        for (int mi = 0; mi < 4; mi++)
            af[mi] = *(const f16x8*)(&As[cur][(wr * 64 + mi * 16 + (lane & 15)) * TBK + (lane >> 4) * 8]);
#pragma unroll
        for (int nj = 0; nj < 4; nj++) {
            int ro = (wc * 64 + nj * 16 + (lane & 15)) * TBK + (lane >> 4) * 8;
            bf1[nj] = *(const f16x8*)(&B1s[cur][ro]);
            bf2[nj] = *(const f16x8*)(&B2s[cur][ro]);
        }
#pragma unroll
        for (int mi = 0; mi < 4; mi++)
#pragma unroll
            for (int nj = 0; nj < 4; nj++) {
                acc1[mi][nj] = __builtin_amdgcn_mfma_f32_16x16x32_f16(af[mi], bf1[nj], acc1[mi][nj], 0, 0, 0);
                acc2[mi][nj] = __builtin_amdgcn_mfma_f32_16x16x32_f16(af[mi], bf2[nj], acc2[mi][nj], 0, 0, 0);
            }
    }

#pragma unroll
    for (int mi = 0; mi < 4; mi++) {
        int mbase = m0 + wr * 64 + mi * 16 + (lane >> 4) * 4;
#pragma unroll
        for (int nj = 0; nj < 4; nj++) {
            int n = n0 + wc * 64 + nj * 16 + (lane & 15);
            if (n < Nout) {
                float bv1 = c1[n], bv2 = c2[n];
#pragma unroll
                for (int r = 0; r < 4; r++) {
                    int m = mbase + r;
                    if (m < M) {
                        float t1 = tanhf(acc1[mi][nj][r] + bv1);
                        float g1 = 1.f / (1.f + expf(-(acc2[mi][nj][r] + bv2)));
                        Y[(size_t)m * Nout + n] = (_Float16)(t1 * g1);
                    }
                }
            }
        }
    }
}

// ---------------- fused sim GEMM + row softmax (Kin <= 128, grid.x == 1), 3-buf pipeline ----------------
// S = P@C^T ; sim = -sqrt(max(pp+cc-2S,1e-12))/denom ; Ah = softmax_row(sim) f16
__global__ __launch_bounds__(256)
void simgemm(const _Float16* __restrict__ A, const _Float16* __restrict__ B,
             const float* __restrict__ Psq, const float* __restrict__ Csq,
             const float* __restrict__ sscale, _Float16* __restrict__ Ah,
             int M, int K, int Kin)
{
    __shared__ _Float16 As[3][TBM * TBK];
    __shared__ _Float16 Bs[3][TBM * TBK];
    __shared__ float redmx[2][TBM];
    __shared__ float redsm[2][TBM];
    const int tid = threadIdx.x;
    const int lane = tid & 63;
    const int wid = tid >> 6;
    const int wr = wid >> 1, wc = wid & 1;
    const int m0 = blockIdx.y * TBM;

    f32x4 acc[4][4] = {};
    const int nt = K / TBK;
    const int lrow = lane >> 2;
    const int lk = (lane & 3) * 8;

    auto stage = [&](int t, int buf) {   // 4 gll per wave
        const int k0 = t * TBK;
#pragma unroll
        for (int q = 0; q < 2; q++) {
            int c = wid * 2 + q;
            int r = c * 16 + lrow;
            int am = min(m0 + r, M - 1);
            int bn = min(r, Kin - 1);
            gll16(A + (size_t)am * K + k0 + lk, &As[buf][c * 512]);
            gll16(B + (size_t)bn * K + k0 + lk, &Bs[buf][c * 512]);
        }
    };

    stage(0, 0);
    if (nt > 1) stage(1, 1);
    for (int t = 0; t < nt; ++t) {
        if (t + 1 < nt) asm volatile("s_waitcnt vmcnt(4)");
        else            asm volatile("s_waitcnt vmcnt(0)");
        __builtin_amdgcn_s_barrier();
        if (t + 2 < nt) stage(t + 2, (t + 2) % 3);
        const int cur = t % 3;
        f16x8 af[4], bf[4];
#pragma unroll
        for (int mi = 0; mi < 4; mi++)
            af[mi] = *(const f16x8*)(&As[cur][(wr * 64 + mi * 16 + (lane & 15)) * TBK + (lane >> 4) * 8]);
#pragma unroll
        for (int nj = 0; nj < 4; nj++)
            bf[nj] = *(const f16x8*)(&Bs[cur][(wc * 64 + nj * 16 + (lane & 15)) * TBK + (lane >> 4) * 8]);
#pragma unroll
        for (int mi = 0; mi < 4; mi++)
#pragma unroll
            for (int nj = 0; nj < 4; nj++)
                acc[mi][nj] = __builtin_amdgcn_mfma_f32_16x16x32_f16(af[mi], bf[nj], acc[mi][nj], 0, 0, 0);
    }
    __syncthreads();   // before epilogue LDS reductions reuse

    const float denom = fmaxf(1e-6f, sscale[0]);
    const int colbase = wc * 64 + (lane & 15);
    const int g = lane >> 4;
    float cc[4];
#pragma unroll
    for (int nj = 0; nj < 4; nj++) {
        int n = colbase + nj * 16;
        cc[nj] = (n < Kin) ? Csq[n] : 0.f;
    }

    // pass 1: sim values into acc, per-row max -> LDS
#pragma unroll
    for (int mi = 0; mi < 4; mi++) {
#pragma unroll
        for (int r = 0; r < 4; r++) {
            int row = wr * 64 + mi * 16 + g * 4 + r;
            float pp = Psq[m0 + row];
            float mx = -INFINITY;
#pragma unroll
            for (int nj = 0; nj < 4; nj++) {
                int n = colbase + nj * 16;
                float v = -INFINITY;
                if (n < Kin)
                    v = -sqrtf(fmaxf(pp + cc[nj] - 2.f * acc[mi][nj][r], 1e-12f)) / denom;
                acc[mi][nj][r] = v;
                mx = fmaxf(mx, v);
            }
#pragma unroll
            for (int o = 1; o < 16; o <<= 1) mx = fmaxf(mx, __shfl_xor(mx, o));
            if ((lane & 15) == 0) redmx[wc][row] = mx;
        }
    }
    __syncthreads();

    // pass 2: exp + per-row sum -> LDS
#pragma unroll
    for (int mi = 0; mi < 4; mi++) {
#pragma unroll
        for (int r = 0; r < 4; r++) {
            int row = wr * 64 + mi * 16 + g * 4 + r;
            float mx = fmaxf(redmx[0][row], redmx[1][row]);
            float s = 0.f;
#pragma unroll
            for (int nj = 0; nj < 4; nj++) {
                int n = colbase + nj * 16;
                float e = (n < Kin) ? expf(acc[mi][nj][r] - mx) : 0.f;
                acc[mi][nj][r] = e;
                s += e;
            }
#pragma unroll
            for (int o = 1; o < 16; o <<= 1) s += __shfl_xor(s, o);
            if ((lane & 15) == 0) redsm[wc][row] = s;
        }
    }
    __syncthreads();

    // pass 3: normalize + write f16
#pragma unroll
    for (int mi = 0; mi < 4; mi++) {
#pragma unroll
        for (int r = 0; r < 4; r++) {
            int row = wr * 64 + mi * 16 + g * 4 + r;
            float inv = 1.f / (redsm[0][row] + redsm[1][row]);
            int m = m0 + row;
#pragma unroll
            for (int nj = 0; nj < 4; nj++) {
                int n = colbase + nj * 16;
                if (n < Kin)
                    Ah[(size_t)m * Kin + n] = (_Float16)(acc[mi][nj][r] * inv);
            }
        }
    }
}

// ---------------- converters ----------------
__global__ __launch_bounds__(256)
void cvt_k(const float* __restrict__ x, _Float16* __restrict__ y, int n)
{
    int i = (blockIdx.x * 256 + threadIdx.x) * 4;
    if (i < n) {
        float4 v = *(const float4*)(x + i);
        f16x4 h = { (_Float16)v.x, (_Float16)v.y, (_Float16)v.z, (_Float16)v.w };
        *(f16x4*)(y + i) = h;
    }
}

// C [Kin,512] fp32 -> Ch [Kin,512] f16 and CTh [512,Kin] f16
__global__ __launch_bounds__(256)
void cvtC_k(const float* __restrict__ C, _Float16* __restrict__ Ch,
            _Float16* __restrict__ CTh, int Kin)
{
    int i = blockIdx.x * 256 + threadIdx.x;
    if (i < Kin * 512) {
        int j = i >> 9, d = i & 511;
        float v = C[i];
        Ch[i] = (_Float16)v;
        CTh[d * Kin + j] = (_Float16)v;
    }
}

// ---------------- small kernels (f16 activations) ----------------
__global__ __launch_bounds__(256)
void rowsq_k(const _Float16* __restrict__ X, float* __restrict__ out, int M)
{
    int wid = threadIdx.x >> 6, lane = threadIdx.x & 63;
    int row = blockIdx.x * 4 + wid;
    if (row >= M) return;
    f16x8 a = *(const f16x8*)(X + (size_t)row * 512 + lane * 8);
    float s = 0.f;
#pragma unroll
    for (int q = 0; q < 8; q++) { float f = (float)a[q]; s += f * f; }
#pragma unroll
    for (int o = 32; o; o >>= 1) s += __shfl_xor(s, o);
    if (lane == 0) out[row] = s;
}

// Yh = LN(X (+R)) * g + b, f16 in/out, fp32 math; one wave per row
__global__ __launch_bounds__(256)
void ln_k(const _Float16* __restrict__ X, const _Float16* __restrict__ R,
          const float* __restrict__ g, const float* __restrict__ b,
          _Float16* __restrict__ Yh, int M)
{
    int wid = threadIdx.x >> 6, lane = threadIdx.x & 63;
    int row = blockIdx.x * 4 + wid;
    if (row >= M) return;
    f16x8 a = *(const f16x8*)(X + (size_t)row * 512 + lane * 8);
    float v[8];
#pragma unroll
    for (int q = 0; q < 8; q++) v[q] = (float)a[q];
    if (R) {
        f16x8 c = *(const f16x8*)(R + (size_t)row * 512 + lane * 8);
#pragma unroll
        for (int q = 0; q < 8; q++) v[q] += (float)c[q];
    }
    float s = 0.f, ss = 0.f;
#pragma unroll
    for (int q = 0; q < 8; q++) { s += v[q]; ss += v[q] * v[q]; }
#pragma unroll
    for (int o = 32; o; o >>= 1) { s += __shfl_xor(s, o); ss += __shfl_xor(ss, o); }
    float mean = s * (1.f / 512.f);
    float var = ss * (1.f / 512.f) - mean * mean;
    float inv = 1.f / sqrtf(var + 1e-5f);
    int d0 = lane * 8;
    f16x8 o8;
#pragma unroll
    for (int q = 0; q < 8; q++)
        o8[q] = (_Float16)((v[q] - mean) * inv * g[d0 + q] + b[d0 + q]);
    *(f16x8*)(Yh + (size_t)row * 512 + d0) = o8;
}

__global__ __launch_bounds__(256)
void red1_k(const float* __restrict__ C, const float* __restrict__ w1,
            const float* __restrict__ b1, float* __restrict__ H1, int Kin)
{
    int d = blockIdx.x * 256 + threadIdx.x;
    int j = blockIdx.y;
    float acc = b1[j];
    for (int k = 0; k < Kin; k++) acc = fmaf(C[(size_t)k * 512 + d], w1[(size_t)j * Kin + k], acc);
    H1[(size_t)j * 512 + d] = fmaxf(acc, 0.f);
}

__global__ __launch_bounds__(256)
void red2_k(const float* __restrict__ H1, const float* __restrict__ w2,
            const float* __restrict__ b2, float* __restrict__ Cn, int Kin, int Kout)
{
    int d = blockIdx.x * 256 + threadIdx.x;
    int j2 = blockIdx.y;
    float acc = b2[j2];
    for (int j = 0; j < Kin; j++) acc = fmaf(H1[(size_t)j * 512 + d], w2[(size_t)j2 * Kin + j], acc);
    Cn[(size_t)j2 * 512 + d] = acc;
}

// scores[i] = dot(TG[i,:], Ws) + bs; TG f16
__global__ __launch_bounds__(256)
void score_k(const _Float16* __restrict__ TG, const float* __restrict__ Ws,
             const float* __restrict__ bs, float* __restrict__ out, int M)
{
    int wid = threadIdx.x >> 6, lane = threadIdx.x & 63;
    int row = blockIdx.x * 4 + wid;
    if (row >= M) return;
    f16x8 a = *(const f16x8*)(TG + (size_t)row * 512 + lane * 8);
    float4 w0 = *(const float4*)(Ws + lane * 8);
    float4 w1 = *(const float4*)(Ws + lane * 8 + 4);
    float d = (float)a[0] * w0.x + (float)a[1] * w0.y + (float)a[2] * w0.z + (float)a[3] * w0.w
            + (float)a[4] * w1.x + (float)a[5] * w1.y + (float)a[6] * w1.z + (float)a[7] * w1.w;
#pragma unroll
    for (int o = 32; o; o >>= 1) d += __shfl_xor(d, o);
    if (lane == 0) out[row] = d + bs[0];
}

__global__ __launch_bounds__(1024)
void pool_k(float* __restrict__ s, float* __restrict__ scal, int M)
{
    __shared__ float sm[16];
    int tid = threadIdx.x, lane = tid & 63, wid = tid >> 6;
    float mx = -INFINITY;
    for (int i = tid * 4; i < M; i += 4096) {
        float4 a = *(const float4*)(s + i);
        mx = fmaxf(fmaxf(fmaxf(mx, a.x), fmaxf(a.y, a.z)), a.w);
    }
#pragma unroll
    for (int o = 32; o; o >>= 1) mx = fmaxf(mx, __shfl_xor(mx, o));
    if (lane == 0) sm[wid] = mx;
    __syncthreads();
    if (wid == 0) {
        float v = (lane < 16) ? sm[lane] : -INFINITY;
#pragma unroll
        for (int o = 8; o; o >>= 1) v = fmaxf(v, __shfl_xor(v, o));
        if (lane == 0) sm[0] = v;
    }
    __syncthreads();
    float gmax = sm[0];
    __syncthreads();
    float sum = 0.f;
    for (int i = tid * 4; i < M; i += 4096) {
        float4 a = *(const float4*)(s + i);
        float4 e;
        e.x = expf(a.x - gmax); e.y = expf(a.y - gmax);
        e.z = expf(a.z - gmax); e.w = expf(a.w - gmax);
        *(float4*)(s + i) = e;
        sum += e.x + e.y + e.z + e.w;
    }
#pragma unroll
    for (int o = 32; o; o >>= 1) sum += __shfl_xor(sum, o);
    if (lane == 0) sm[wid] = sum;
    __syncthreads();
    if (tid == 0) {
        float t = 0.f;
        for (int w = 0; w < 16; w++) t += sm[w];
        scal[0] = t;
    }
}

__global__ __launch_bounds__(256)
void bagp_k(const _Float16* __restrict__ Z, const float* __restrict__ w,
            float* __restrict__ PB, int M, int cs)
{
    int d = blockIdx.x * 256 + threadIdx.x;
    int chunk = blockIdx.y;
    int i0 = chunk * cs;
    int i1 = min(M, i0 + cs);
    float acc = 0.f;
    for (int i = i0; i < i1; i++) acc = fmaf(w[i], (float)Z[(size_t)i * 512 + d], acc);
    PB[(size_t)chunk * 512 + d] = acc;
}

__global__ __launch_bounds__(256)
void bagf_k(const float* __restrict__ PB, const float* __restrict__ scal,
            float* __restrict__ bag, int nchunk)
{
    int d = blockIdx.x * 256 + threadIdx.x;
    float acc = 0.f;
    for (int c = 0; c < nchunk; c++) acc += PB[(size_t)c * 512 + d];
    bag[d] = acc / scal[0];
}

__global__ __launch_bounds__(256)
void h_k(const float* __restrict__ bag, const float* __restrict__ Wh,
         const float* __restrict__ bh, float* __restrict__ h)
{
    int wid = threadIdx.x >> 6, lane = threadIdx.x & 63;
    int j = blockIdx.x * 4 + wid;
    const float* wr = Wh + (size_t)j * 512;
    float d = 0.f;
#pragma unroll
    for (int t = 0; t < 2; t++) {
        float4 a = *(const float4*)(wr + t * 256 + lane * 4);
        float4 bv = *(const float4*)(bag + t * 256 + lane * 4);
        d += a.x * bv.x + a.y * bv.y + a.z * bv.z + a.w * bv.w;
    }
#pragma unroll
    for (int o = 32; o; o >>= 1) d += __shfl_xor(d, o);
    if (lane == 0) h[j] = fmaxf(d + bh[j], 0.f);
}

__global__ __launch_bounds__(128)
void logit_k(const float* __restrict__ h, const float* __restrict__ Wc,
             const float* __restrict__ bc, float* __restrict__ out)
{
    int wid = threadIdx.x >> 6, lane = threadIdx.x & 63;
    const float* wr = Wc + (size_t)wid * 512;
    float d = 0.f;
#pragma unroll
    for (int t = 0; t < 2; t++) {
        float4 a = *(const float4*)(wr + t * 256 + lane * 4);
        float4 hv = *(const float4*)(h + t * 256 + lane * 4);
        d += a.x * hv.x + a.y * hv.y + a.z * hv.z + a.w * hv.w;
    }
#pragma unroll
    for (int o = 32; o; o >>= 1) d += __shfl_xor(d, o);
    if (lane == 0) out[wid] = d + bc[wid];
}

extern "C" void kernel_launch(void* const* d_in, const int* in_sizes, int n_in,
                              void* d_out, int out_size, void* d_ws, size_t ws_size,
                              hipStream_t stream)
{
    const float* data    = (const float*)d_in[0];
    const float* protos  = (const float*)d_in[1];
    const float* W_pp    = (const float*)d_in[2];
    const float* b_pp    = (const float*)d_in[3];
    const float* W_cp    = (const float*)d_in[4];
    const float* b_cp    = (const float*)d_in[5];
    const float* sscale  = (const float*)d_in[6];
    const float* enh_w1  = (const float*)d_in[7];
    const float* enh_b1  = (const float*)d_in[8];
    const float* enh_w2  = (const float*)d_in[9];
    const float* enh_b2  = (const float*)d_in[10];
    const float* ln_g    = (const float*)d_in[11];
    const float* ln_b    = (const float*)d_in[12];
    const float* red_w1[3] = {(const float*)d_in[13], (const float*)d_in[17], (const float*)d_in[21]};
    const float* red_b1[3] = {(const float*)d_in[14], (const float*)d_in[18], (const float*)d_in[22]};
    const float* red_w2[3] = {(const float*)d_in[15], (const float*)d_in[19], (const float*)d_in[23]};
    const float* red_b2[3] = {(const float*)d_in[16], (const float*)d_in[20], (const float*)d_in[24]};
    const float* W_proc  = (const float*)d_in[25];
    const float* b_proc  = (const float*)d_in[26];
    const float* g_an    = (const float*)d_in[27];
    const float* b_an    = (const float*)d_in[28];
    const float* W_t     = (const float*)d_in[29];
    const float* b_t     = (const float*)d_in[30];
    const float* W_g     = (const float*)d_in[31];
    const float* b_g     = (const float*)d_in[32];
    const float* W_s     = (const float*)d_in[33];
    const float* b_s     = (const float*)d_in[34];
    const float* W_h     = (const float*)d_in[35];
    const float* b_h     = (const float*)d_in[36];
    const float* W_c     = (const float*)d_in[37];
    const float* b_c     = (const float*)d_in[38];
    float* out = (float*)d_out;

    constexpr int N = 32768, DIN = 768, D = 512;
    constexpr int NCHUNK = 256;
    char* w = (char*)d_ws;
    auto alloc = [&](size_t bytes) -> char* {
        char* p = w; w += (bytes + 255) & ~(size_t)255; return p;
    };
    _Float16* Ph     = (_Float16*)alloc((size_t)N * D * 2);
    _Float16* CTXh   = (_Float16*)alloc((size_t)N * D * 2);
    _Float16* TMPh   = (_Float16*)alloc((size_t)N * D * 2);
    _Float16* Zrawh  = (_Float16*)alloc((size_t)(N + 16) * D * 2);
    _Float16* Zh     = (_Float16*)alloc((size_t)(N + 16) * D * 2);
    _Float16* TGh    = (_Float16*)alloc((size_t)(N + 16) * D * 2);
    _Float16* datah  = (_Float16*)alloc((size_t)N * DIN * 2);
    _Float16* Ah     = (_Float16*)alloc((size_t)N * 128 * 2);
    _Float16* Ch     = (_Float16*)alloc(128 * D * 2);
    _Float16* CTh    = (_Float16*)alloc(128 * D * 2);
    _Float16* Wpph   = (_Float16*)alloc((size_t)D * DIN * 2);
    _Float16* w1h    = (_Float16*)alloc((size_t)3 * D * D * 2);
    _Float16* w2h    = (_Float16*)alloc((size_t)3 * D * D * 2);
    _Float16* Wproch = (_Float16*)alloc((size_t)D * D * 2);
    _Float16* Wth    = (_Float16*)alloc((size_t)D * D * 2);
    _Float16* Wgh    = (_Float16*)alloc((size_t)D * D * 2);
    float*    Psq    = (float*)alloc((size_t)N * 4);
    float*    Csq    = (float*)alloc(128 * 4);
    float*    Ca     = (float*)alloc(128 * D * 4);
    float*    Cb     = (float*)alloc(128 * D * 4);
    float*    H1     = (float*)alloc(128 * D * 4);
    float*    scr    = (float*)alloc((size_t)(N + 16) * 4);
    float*    PB     = (float*)alloc((size_t)NCHUNK * D * 4);
    float*    bag    = (float*)alloc(D * 4);
    float*    hb     = (float*)alloc(D * 4);
    float*    scal   = (float*)alloc(8 * 4);

    dim3 blk(256);
    auto cgrid = [](size_t n) { return dim3((unsigned)((n / 4 + 255) / 256)); };
    auto mgrid = [](int M_, int Nout_) { return dim3((Nout_ + TBN - 1) / TBN, (M_ + TBM - 1) / TBM); };

    // --- convert weights + data to f16 ---
    cvt_k<<<cgrid((size_t)N * DIN), blk, 0, stream>>>(data, datah, N * DIN);
    cvt_k<<<cgrid((size_t)D * DIN), blk, 0, stream>>>(W_pp, Wpph, D * DIN);
    cvt_k<<<cgrid((size_t)3 * D * D), blk, 0, stream>>>(enh_w1, w1h, 3 * D * D);
    cvt_k<<<cgrid((size_t)3 * D * D), blk, 0, stream>>>(enh_w2, w2h, 3 * D * D);
    cvt_k<<<cgrid((size_t)D * D), blk, 0, stream>>>(W_proc, Wproch, D * D);
    cvt_k<<<cgrid((size_t)D * D), blk, 0, stream>>>(W_t, Wth, D * D);
    cvt_k<<<cgrid((size_t)D * D), blk, 0, stream>>>(W_g, Wgh, D * D);

    // P = leaky(data @ W_pp^T + b_pp) -> f16
    mgemm<0, 1, false><<<mgrid(N, D), blk, 0, stream>>>(datah, Wpph, b_pp, Ph, nullptr, N, DIN, D);
    // C0 = leaky(protos @ W_cp^T + b_cp) -> fp32 (tiny)
    dot_k<1, false><<<dim3(128 * 512 / 4), blk, 0, stream>>>(protos, W_cp, b_cp, Ca, 128, DIN);

    float* C = Ca;
    float* Cn = Cb;
    int Kin = 128;
    for (int i = 0; i < 3; i++) {
        int Kout = Kin >> 1;
        rowsq_k<<<dim3((N + 3) / 4), blk, 0, stream>>>(Ph, Psq, N);
        cvtC_k<<<dim3((Kin * D + 255) / 256), blk, 0, stream>>>(C, Ch, CTh, Kin);
        rowsq_k<<<dim3((Kin + 3) / 4), blk, 0, stream>>>(Ch, Csq, Kin);
        // A = softmax(-dist/denom) fused with S = P@C^T
        simgemm<<<dim3(1, N / TBM), blk, 0, stream>>>(Ph, Ch, Psq, Csq, sscale, Ah, N, D, Kin);
        // ctx = A @ C -> f16
        mgemm<0, 0, false><<<mgrid(N, D), blk, 0, stream>>>(Ah, CTh, nullptr, CTXh, nullptr, N, Kin, D);
        // P = LN(P + ctx) -> f16
        ln_k<<<dim3((N + 3) / 4), blk, 0, stream>>>(Ph, CTXh, ln_g + (size_t)i * D, ln_b + (size_t)i * D, Ph, N);
        // enhancer MLP: P += w2 @ relu(w1 @ P + b1) + b2
        mgemm<0, 2, false><<<mgrid(N, D), blk, 0, stream>>>(Ph, w1h + (size_t)i * D * D, enh_b1 + (size_t)i * D, TMPh, nullptr, N, D, D);
        mgemm<1, 0, false><<<mgrid(N, D), blk, 0, stream>>>(TMPh, w2h + (size_t)i * D * D, enh_b2 + (size_t)i * D, Ph, nullptr, N, D, D);
        // ProtoReducer (fp32, tiny)
        red1_k<<<dim3(2, Kin), blk, 0, stream>>>(C, red_w1[i], red_b1[i], H1, Kin);
        red2_k<<<dim3(2, Kout), blk, 0, stream>>>(H1, red_w2[i], red_b2[i], Cn, Kin, Kout);
        float* t = C; C = Cn; Cn = t;
        Kin = Kout;
    }

    // Zraw = relu(proc([P; C]))
    mgemm<0, 2, false><<<mgrid(N, D), blk, 0, stream>>>(Ph, Wproch, b_proc, Zrawh, nullptr, N, D, D);
    dot_k<2, true><<<dim3(16 * 512 / 4), blk, 0, stream>>>(C, W_proc, b_proc, Zrawh + (size_t)N * D, 16, D);
    // Z = LN(Zraw)
    ln_k<<<dim3((N + 16 + 3) / 4), blk, 0, stream>>>(Zrawh, nullptr, g_an, b_an, Zh, N + 16);

    // TG = tanh(Z@W_t^T+b_t) * sigmoid(Z@W_g^T+b_g)  (fused dual GEMM)
    gatgemm<<<mgrid(N + 16, D), blk, 0, stream>>>(Zh, Wth, Wgh, b_t, b_g, TGh, N + 16, D, D);

    // attention pooling
    score_k<<<dim3((N + 16 + 3) / 4), blk, 0, stream>>>(TGh, W_s, b_s, scr, N + 16);
    pool_k<<<dim3(1), dim3(1024), 0, stream>>>(scr, scal, N + 16);
    int cs = (N + 16 + NCHUNK - 1) / NCHUNK;
    bagp_k<<<dim3(2, NCHUNK), blk, 0, stream>>>(Zh, scr, PB, N + 16, cs);
    bagf_k<<<dim3(2), blk, 0, stream>>>(PB, scal, bag, NCHUNK);

    // classifier head
    h_k<<<dim3(128), blk, 0, stream>>>(bag, W_h, b_h, hb);
    logit_k<<<dim3(1), dim3(128), 0, stream>>>(hb, W_c, b_c, out);
}

// Round 9
// 914.792 us; speedup vs baseline: 1.7179x; 1.2520x over previous
//
#include <hip/hip_runtime.h>
#include <math.h>

typedef _Float16 f16x8 __attribute__((ext_vector_type(8)));
typedef _Float16 f16x4 __attribute__((ext_vector_type(4)));
typedef float f32x4 __attribute__((ext_vector_type(4)));

#define TBM 256
#define TBN 128
#define TBK 32

#define AS1 __attribute__((address_space(1)))
#define AS3 __attribute__((address_space(3)))

__device__ __forceinline__ void gll16(const _Float16* g, _Float16* l)
{
    // direct global->LDS, 16B per lane; LDS dest = wave-uniform base + lane*16
    __builtin_amdgcn_global_load_lds((const AS1 unsigned int*)g,
                                     (AS3 unsigned int*)l, 16, 0, 0);
}

// XCD-aware bijective swizzle of linear block id (nwg % 8 == 0 required for effect)
__device__ __forceinline__ int xcd_swz(int bid, int nwg)
{
    if ((nwg & 7) == 0) {
        int chunk = nwg >> 3;
        bid = (bid & 7) * chunk + (bid >> 3);
    }
    return bid;
}

// ---------------- wave-per-output dot kernel (small-M fp32 GEMMs) ----------------
// ACT: 1 leaky, 2 relu ; F16OUT selects output dtype
template<int ACT, bool F16OUT>
__global__ __launch_bounds__(256)
void dot_k(const float* __restrict__ X, const float* __restrict__ W,
           const float* __restrict__ bias, void* __restrict__ Yv,
           int M, int K)
{
    int gw = (blockIdx.x * 256 + threadIdx.x) >> 6;
    int lane = threadIdx.x & 63;
    if (gw >= M * 512) return;
    int r = gw >> 9, n = gw & 511;
    const float* xr = X + (size_t)r * K;
    const float* wr = W + (size_t)n * K;
    float d = 0.f;
    for (int t = 0; t < K; t += 256) {
        float4 a = *(const float4*)(xr + t + lane * 4);
        float4 b = *(const float4*)(wr + t + lane * 4);
        d += a.x * b.x + a.y * b.y + a.z * b.z + a.w * b.w;
    }
#pragma unroll
    for (int o = 32; o; o >>= 1) d += __shfl_xor(d, o);
    if (lane == 0) {
        float v = d + bias[n];
        if (ACT == 1) v = v > 0.f ? v : 0.01f * v;
        else if (ACT == 2) v = fmaxf(v, 0.f);
        if (F16OUT) ((_Float16*)Yv)[(size_t)r * 512 + n] = (_Float16)v;
        else        ((float*)Yv)[(size_t)r * 512 + n] = v;
    }
}

// ---------------- f16 MFMA GEMM: 256x128 tile, 8 waves, LDS dbuf ----------------
// v[m,n] = sum_k A[m,k]*B[n,k] + bias[n]
// MODE 0: out = act(v) -> Yh f16 (or Yf fp32 if F32OUT); MODE 1: out = Yh + v
// ACT: 0 none, 1 leaky, 2 relu
template<int MODE, int ACT, bool F32OUT>
__global__ __launch_bounds__(512)
void mgemm(const _Float16* __restrict__ A, const _Float16* __restrict__ B,
           const float* __restrict__ bias, _Float16* __restrict__ Yh,
           float* __restrict__ Yf, int M, int K, int Nout)
{
    __shared__ _Float16 As[2][TBM * TBK];   // 16 KB each
    __shared__ _Float16 Bs[2][TBN * TBK];   // 8 KB each
    const int tid = threadIdx.x;
    const int lane = tid & 63;
    const int wid = tid >> 6;               // 0..7
    const int wr = wid >> 1, wc = wid & 1;  // 4 x 2 wave grid

    int bid = xcd_swz(blockIdx.y * gridDim.x + blockIdx.x, gridDim.x * gridDim.y);
    const int m0 = (bid / gridDim.x) * TBM;
    const int n0 = (bid % gridDim.x) * TBN;

    f32x4 acc[4][4] = {};
    const int nt = K / TBK;

    const int lrow = lane >> 2;          // 0..15 row within chunk
    const int lk = (lane & 3) * 8;       // f16 offset within 32-elem k slab

    auto stage = [&](int t, int buf) {   // 3 gll per thread
        const int k0 = t * TBK;
#pragma unroll
        for (int q = 0; q < 2; q++) {
            int c = wid * 2 + q;                      // 0..15 (A chunks)
            int r = c * 16 + lrow;
            int am = min(m0 + r, M - 1);
            gll16(A + (size_t)am * K + k0 + lk, &As[buf][c * 512]);
        }
        {
            int c = wid;                              // 0..7 (B chunks)
            int r = c * 16 + lrow;
            int bn = min(n0 + r, Nout - 1);
            gll16(B + (size_t)bn * K + k0 + lk, &Bs[buf][c * 512]);
        }
    };

    stage(0, 0);
    __syncthreads();
    for (int t = 0; t < nt; ++t) {
        const int cur = t & 1;
        if (t + 1 < nt) stage(t + 1, cur ^ 1);
        f16x8 af[4], bf[4];
#pragma unroll
        for (int mi = 0; mi < 4; mi++)
            af[mi] = *(const f16x8*)(&As[cur][(wr * 64 + mi * 16 + (lane & 15)) * TBK + (lane >> 4) * 8]);
#pragma unroll
        for (int nj = 0; nj < 4; nj++)
            bf[nj] = *(const f16x8*)(&Bs[cur][(wc * 64 + nj * 16 + (lane & 15)) * TBK + (lane >> 4) * 8]);
#pragma unroll
        for (int mi = 0; mi < 4; mi++)
#pragma unroll
            for (int nj = 0; nj < 4; nj++)
                acc[mi][nj] = __builtin_amdgcn_mfma_f32_16x16x32_f16(af[mi], bf[nj], acc[mi][nj], 0, 0, 0);
        __syncthreads();
    }

#pragma unroll
    for (int mi = 0; mi < 4; mi++) {
        int mbase = m0 + wr * 64 + mi * 16 + (lane >> 4) * 4;
#pragma unroll
        for (int nj = 0; nj < 4; nj++) {
            int n = n0 + wc * 64 + nj * 16 + (lane & 15);
            if (n < Nout) {
                float bv = bias ? bias[n] : 0.f;
#pragma unroll
                for (int r = 0; r < 4; r++) {
                    int m = mbase + r;
                    if (m < M) {
                        float v = acc[mi][nj][r] + bv;
                        size_t idx = (size_t)m * Nout + n;
                        if (MODE == 0) {
                            if (ACT == 1) v = v > 0.f ? v : 0.01f * v;
                            else if (ACT == 2) v = fmaxf(v, 0.f);
                            if (F32OUT) Yf[idx] = v;
                            else        Yh[idx] = (_Float16)v;
                        } else {
                            float s = (float)Yh[idx] + v;
                            Yh[idx] = (_Float16)s;
                        }
                    }
                }
            }
        }
    }
}

// ---------------- fused dual gate GEMM: 256x128 tile, 8 waves ----------------
__global__ __launch_bounds__(512)
void gatgemm(const _Float16* __restrict__ A, const _Float16* __restrict__ B1,
             const _Float16* __restrict__ B2, const float* __restrict__ c1,
             const float* __restrict__ c2, _Float16* __restrict__ Y,
             int M, int K, int Nout)
{
    __shared__ _Float16 As[2][TBM * TBK];
    __shared__ _Float16 B1s[2][TBN * TBK];
    __shared__ _Float16 B2s[2][TBN * TBK];
    const int tid = threadIdx.x;
    const int lane = tid & 63;
    const int wid = tid >> 6;
    const int wr = wid >> 1, wc = wid & 1;

    int bid = xcd_swz(blockIdx.y * gridDim.x + blockIdx.x, gridDim.x * gridDim.y);
    const int m0 = (bid / gridDim.x) * TBM;
    const int n0 = (bid % gridDim.x) * TBN;

    f32x4 acc1[4][4] = {};
    f32x4 acc2[4][4] = {};
    const int nt = K / TBK;

    const int lrow = lane >> 2;
    const int lk = (lane & 3) * 8;

    auto stage = [&](int t, int buf) {   // 4 gll per thread
        const int k0 = t * TBK;
#pragma unroll
        for (int q = 0; q < 2; q++) {
            int c = wid * 2 + q;
            int r = c * 16 + lrow;
            int am = min(m0 + r, M - 1);
            gll16(A + (size_t)am * K + k0 + lk, &As[buf][c * 512]);
        }
        {
            int c = wid;
            int r = c * 16 + lrow;
            int bn = min(n0 + r, Nout - 1);
            gll16(B1 + (size_t)bn * K + k0 + lk, &B1s[buf][c * 512]);
            gll16(B2 + (size_t)bn * K + k0 + lk, &B2s[buf][c * 512]);
        }
    };

    stage(0, 0);
    __syncthreads();
    for (int t = 0; t < nt; ++t) {
        const int cur = t & 1;
        if (t + 1 < nt) stage(t + 1, cur ^ 1);
        f16x8 af[4], bf1[4], bf2[4];
#pragma unroll
        for (int mi = 0; mi < 4; mi++)
            af[mi] = *(const f16x8*)(&As[cur][(wr * 64 + mi * 16 + (lane & 15)) * TBK + (lane >> 4) * 8]);
#pragma unroll
        for (int nj = 0; nj < 4; nj++) {
            int ro = (wc * 64 + nj * 16 + (lane & 15)) * TBK + (lane >> 4) * 8;
            bf1[nj] = *(const f16x8*)(&B1s[cur][ro]);
            bf2[nj] = *(const f16x8*)(&B2s[cur][ro]);
        }
#pragma unroll
        for (int mi = 0; mi < 4; mi++)
#pragma unroll
            for (int nj = 0; nj < 4; nj++) {
                acc1[mi][nj] = __builtin_amdgcn_mfma_f32_16x16x32_f16(af[mi], bf1[nj], acc1[mi][nj], 0, 0, 0);
                acc2[mi][nj] = __builtin_amdgcn_mfma_f32_16x16x32_f16(af[mi], bf2[nj], acc2[mi][nj], 0, 0, 0);
            }
        __syncthreads();
    }

#pragma unroll
    for (int mi = 0; mi < 4; mi++) {
        int mbase = m0 + wr * 64 + mi * 16 + (lane >> 4) * 4;
#pragma unroll
        for (int nj = 0; nj < 4; nj++) {
            int n = n0 + wc * 64 + nj * 16 + (lane & 15);
            if (n < Nout) {
                float bv1 = c1[n], bv2 = c2[n];
#pragma unroll
                for (int r = 0; r < 4; r++) {
                    int m = mbase + r;
                    if (m < M) {
                        float t1 = tanhf(acc1[mi][nj][r] + bv1);
                        float g1 = 1.f / (1.f + expf(-(acc2[mi][nj][r] + bv2)));
                        Y[(size_t)m * Nout + n] = (_Float16)(t1 * g1);
                    }
                }
            }
        }
    }
}

// ---------------- fused sim GEMM + row softmax: 256-row blocks, 8 waves ----------------
// S = P@C^T ; sim = -sqrt(max(pp+cc-2S,1e-12))/denom ; Ah = softmax_row(sim) f16
__global__ __launch_bounds__(512)
void simgemm(const _Float16* __restrict__ A, const _Float16* __restrict__ B,
             const float* __restrict__ Psq, const float* __restrict__ Csq,
             const float* __restrict__ sscale, _Float16* __restrict__ Ah,
             int M, int K, int Kin)
{
    __shared__ _Float16 As[2][TBM * TBK];
    __shared__ _Float16 Bs[2][TBN * TBK];
    __shared__ float redmx[2][TBM];
    __shared__ float redsm[2][TBM];
    const int tid = threadIdx.x;
    const int lane = tid & 63;
    const int wid = tid >> 6;
    const int wr = wid >> 1, wc = wid & 1;
    const int m0 = blockIdx.y * TBM;

    f32x4 acc[4][4] = {};
    const int nt = K / TBK;
    const int lrow = lane >> 2;
    const int lk = (lane & 3) * 8;

    auto stage = [&](int t, int buf) {
        const int k0 = t * TBK;
#pragma unroll
        for (int q = 0; q < 2; q++) {
            int c = wid * 2 + q;
            int r = c * 16 + lrow;
            int am = min(m0 + r, M - 1);
            gll16(A + (size_t)am * K + k0 + lk, &As[buf][c * 512]);
        }
        {
            int c = wid;
            int r = c * 16 + lrow;
            int bn = min(r, Kin - 1);
            gll16(B + (size_t)bn * K + k0 + lk, &Bs[buf][c * 512]);
        }
    };

    stage(0, 0);
    __syncthreads();
    for (int t = 0; t < nt; ++t) {
        const int cur = t & 1;
        if (t + 1 < nt) stage(t + 1, cur ^ 1);
        f16x8 af[4], bf[4];
#pragma unroll
        for (int mi = 0; mi < 4; mi++)
            af[mi] = *(const f16x8*)(&As[cur][(wr * 64 + mi * 16 + (lane & 15)) * TBK + (lane >> 4) * 8]);
#pragma unroll
        for (int nj = 0; nj < 4; nj++)
            bf[nj] = *(const f16x8*)(&Bs[cur][(wc * 64 + nj * 16 + (lane & 15)) * TBK + (lane >> 4) * 8]);
#pragma unroll
        for (int mi = 0; mi < 4; mi++)
#pragma unroll
            for (int nj = 0; nj < 4; nj++)
                acc[mi][nj] = __builtin_amdgcn_mfma_f32_16x16x32_f16(af[mi], bf[nj], acc[mi][nj], 0, 0, 0);
        __syncthreads();
    }

    const float denom = fmaxf(1e-6f, sscale[0]);
    const int colbase = wc * 64 + (lane & 15);
    const int g = lane >> 4;
    float cc[4];
#pragma unroll
    for (int nj = 0; nj < 4; nj++) {
        int n = colbase + nj * 16;
        cc[nj] = (n < Kin) ? Csq[n] : 0.f;
    }

    // pass 1: sim values into acc, per-row max -> LDS
#pragma unroll
    for (int mi = 0; mi < 4; mi++) {
#pragma unroll
        for (int r = 0; r < 4; r++) {
            int row = wr * 64 + mi * 16 + g * 4 + r;
            float pp = Psq[m0 + row];
            float mx = -INFINITY;
#pragma unroll
            for (int nj = 0; nj < 4; nj++) {
                int n = colbase + nj * 16;
                float v = -INFINITY;
                if (n < Kin)
                    v = -sqrtf(fmaxf(pp + cc[nj] - 2.f * acc[mi][nj][r], 1e-12f)) / denom;
                acc[mi][nj][r] = v;
                mx = fmaxf(mx, v);
            }
#pragma unroll
            for (int o = 1; o < 16; o <<= 1) mx = fmaxf(mx, __shfl_xor(mx, o));
            if ((lane & 15) == 0) redmx[wc][row] = mx;
        }
    }
    __syncthreads();

    // pass 2: exp + per-row sum -> LDS
#pragma unroll
    for (int mi = 0; mi < 4; mi++) {
#pragma unroll
        for (int r = 0; r < 4; r++) {
            int row = wr * 64 + mi * 16 + g * 4 + r;
            float mx = fmaxf(redmx[0][row], redmx[1][row]);
            float s = 0.f;
#pragma unroll
            for (int nj = 0; nj < 4; nj++) {
                int n = colbase + nj * 16;
                float e = (n < Kin) ? expf(acc[mi][nj][r] - mx) : 0.f;
                acc[mi][nj][r] = e;
                s += e;
            }
#pragma unroll
            for (int o = 1; o < 16; o <<= 1) s += __shfl_xor(s, o);
            if ((lane & 15) == 0) redsm[wc][row] = s;
        }
    }
    __syncthreads();

    // pass 3: normalize + write f16
#pragma unroll
    for (int mi = 0; mi < 4; mi++) {
#pragma unroll
        for (int r = 0; r < 4; r++) {
            int row = wr * 64 + mi * 16 + g * 4 + r;
            float inv = 1.f / (redsm[0][row] + redsm[1][row]);
            int m = m0 + row;
#pragma unroll
            for (int nj = 0; nj < 4; nj++) {
                int n = colbase + nj * 16;
                if (n < Kin)
                    Ah[(size_t)m * Kin + n] = (_Float16)(acc[mi][nj][r] * inv);
            }
        }
    }
}

// ---------------- converters ----------------
__global__ __launch_bounds__(256)
void cvt_k(const float* __restrict__ x, _Float16* __restrict__ y, int n)
{
    int i = (blockIdx.x * 256 + threadIdx.x) * 4;
    if (i < n) {
        float4 v = *(const float4*)(x + i);
        f16x4 h = { (_Float16)v.x, (_Float16)v.y, (_Float16)v.z, (_Float16)v.w };
        *(f16x4*)(y + i) = h;
    }
}

// C [Kin,512] fp32 -> Ch [Kin,512] f16 and CTh [512,Kin] f16
__global__ __launch_bounds__(256)
void cvtC_k(const float* __restrict__ C, _Float16* __restrict__ Ch,
            _Float16* __restrict__ CTh, int Kin)
{
    int i = blockIdx.x * 256 + threadIdx.x;
    if (i < Kin * 512) {
        int j = i >> 9, d = i & 511;
        float v = C[i];
        Ch[i] = (_Float16)v;
        CTh[d * Kin + j] = (_Float16)v;
    }
}

// ---------------- small kernels (f16 activations) ----------------
__global__ __launch_bounds__(256)
void rowsq_k(const _Float16* __restrict__ X, float* __restrict__ out, int M)
{
    int wid = threadIdx.x >> 6, lane = threadIdx.x & 63;
    int row = blockIdx.x * 4 + wid;
    if (row >= M) return;
    f16x8 a = *(const f16x8*)(X + (size_t)row * 512 + lane * 8);
    float s = 0.f;
#pragma unroll
    for (int q = 0; q < 8; q++) { float f = (float)a[q]; s += f * f; }
#pragma unroll
    for (int o = 32; o; o >>= 1) s += __shfl_xor(s, o);
    if (lane == 0) out[row] = s;
}

// Yh = LN(X (+R)) * g + b, f16 in/out, fp32 math; one wave per row
__global__ __launch_bounds__(256)
void ln_k(const _Float16* __restrict__ X, const _Float16* __restrict__ R,
          const float* __restrict__ g, const float* __restrict__ b,
          _Float16* __restrict__ Yh, int M)
{
    int wid = threadIdx.x >> 6, lane = threadIdx.x & 63;
    int row = blockIdx.x * 4 + wid;
    if (row >= M) return;
    f16x8 a = *(const f16x8*)(X + (size_t)row * 512 + lane * 8);
    float v[8];
#pragma unroll
    for (int q = 0; q < 8; q++) v[q] = (float)a[q];
    if (R) {
        f16x8 c = *(const f16x8*)(R + (size_t)row * 512 + lane * 8);
#pragma unroll
        for (int q = 0; q < 8; q++) v[q] += (float)c[q];
    }
    float s = 0.f, ss = 0.f;
#pragma unroll
    for (int q = 0; q < 8; q++) { s += v[q]; ss += v[q] * v[q]; }
#pragma unroll
    for (int o = 32; o; o >>= 1) { s += __shfl_xor(s, o); ss += __shfl_xor(ss, o); }
    float mean = s * (1.f / 512.f);
    float var = ss * (1.f / 512.f) - mean * mean;
    float inv = 1.f / sqrtf(var + 1e-5f);
    int d0 = lane * 8;
    f16x8 o8;
#pragma unroll
    for (int q = 0; q < 8; q++)
        o8[q] = (_Float16)((v[q] - mean) * inv * g[d0 + q] + b[d0 + q]);
    *(f16x8*)(Yh + (size_t)row * 512 + d0) = o8;
}

__global__ __launch_bounds__(256)
void red1_k(const float* __restrict__ C, const float* __restrict__ w1,
            const float* __restrict__ b1, float* __restrict__ H1, int Kin)
{
    int d = blockIdx.x * 256 + threadIdx.x;
    int j = blockIdx.y;
    float acc = b1[j];
    for (int k = 0; k < Kin; k++) acc = fmaf(C[(size_t)k * 512 + d], w1[(size_t)j * Kin + k], acc);
    H1[(size_t)j * 512 + d] = fmaxf(acc, 0.f);
}

__global__ __launch_bounds__(256)
void red2_k(const float* __restrict__ H1, const float* __restrict__ w2,
            const float* __restrict__ b2, float* __restrict__ Cn, int Kin, int Kout)
{
    int d = blockIdx.x * 256 + threadIdx.x;
    int j2 = blockIdx.y;
    float acc = b2[j2];
    for (int j = 0; j < Kin; j++) acc = fmaf(H1[(size_t)j * 512 + d], w2[(size_t)j2 * Kin + j], acc);
    Cn[(size_t)j2 * 512 + d] = acc;
}

// scores[i] = dot(TG[i,:], Ws) + bs; TG f16
__global__ __launch_bounds__(256)
void score_k(const _Float16* __restrict__ TG, const float* __restrict__ Ws,
             const float* __restrict__ bs, float* __restrict__ out, int M)
{
    int wid = threadIdx.x >> 6, lane = threadIdx.x & 63;
    int row = blockIdx.x * 4 + wid;
    if (row >= M) return;
    f16x8 a = *(const f16x8*)(TG + (size_t)row * 512 + lane * 8);
    float4 w0 = *(const float4*)(Ws + lane * 8);
    float4 w1 = *(const float4*)(Ws + lane * 8 + 4);
    float d = (float)a[0] * w0.x + (float)a[1] * w0.y + (float)a[2] * w0.z + (float)a[3] * w0.w
            + (float)a[4] * w1.x + (float)a[5] * w1.y + (float)a[6] * w1.z + (float)a[7] * w1.w;
#pragma unroll
    for (int o = 32; o; o >>= 1) d += __shfl_xor(d, o);
    if (lane == 0) out[row] = d + bs[0];
}

__global__ __launch_bounds__(1024)
void pool_k(float* __restrict__ s, float* __restrict__ scal, int M)
{
    __shared__ float sm[16];
    int tid = threadIdx.x, lane = tid & 63, wid = tid >> 6;
    float mx = -INFINITY;
    for (int i = tid * 4; i < M; i += 4096) {
        float4 a = *(const float4*)(s + i);
        mx = fmaxf(fmaxf(fmaxf(mx, a.x), fmaxf(a.y, a.z)), a.w);
    }
#pragma unroll
    for (int o = 32; o; o >>= 1) mx = fmaxf(mx, __shfl_xor(mx, o));
    if (lane == 0) sm[wid] = mx;
    __syncthreads();
    if (wid == 0) {
        float v = (lane < 16) ? sm[lane] : -INFINITY;
#pragma unroll
        for (int o = 8; o; o >>= 1) v = fmaxf(v, __shfl_xor(v, o));
        if (lane == 0) sm[0] = v;
    }
    __syncthreads();
    float gmax = sm[0];
    __syncthreads();
    float sum = 0.f;
    for (int i = tid * 4; i < M; i += 4096) {
        float4 a = *(const float4*)(s + i);
        float4 e;
        e.x = expf(a.x - gmax); e.y = expf(a.y - gmax);
        e.z = expf(a.z - gmax); e.w = expf(a.w - gmax);
        *(float4*)(s + i) = e;
        sum += e.x + e.y + e.z + e.w;
    }
#pragma unroll
    for (int o = 32; o; o >>= 1) sum += __shfl_xor(sum, o);
    if (lane == 0) sm[wid] = sum;
    __syncthreads();
    if (tid == 0) {
        float t = 0.f;
        for (int w = 0; w < 16; w++) t += sm[w];
        scal[0] = t;
    }
}

__global__ __launch_bounds__(256)
void bagp_k(const _Float16* __restrict__ Z, const float* __restrict__ w,
            float* __restrict__ PB, int M, int cs)
{
    int d = blockIdx.x * 256 + threadIdx.x;
    int chunk = blockIdx.y;
    int i0 = chunk * cs;
    int i1 = min(M, i0 + cs);
    float acc = 0.f;
    for (int i = i0; i < i1; i++) acc = fmaf(w[i], (float)Z[(size_t)i * 512 + d], acc);
    PB[(size_t)chunk * 512 + d] = acc;
}

__global__ __launch_bounds__(256)
void bagf_k(const float* __restrict__ PB, const float* __restrict__ scal,
            float* __restrict__ bag, int nchunk)
{
    int d = blockIdx.x * 256 + threadIdx.x;
    float acc = 0.f;
    for (int c = 0; c < nchunk; c++) acc += PB[(size_t)c * 512 + d];
    bag[d] = acc / scal[0];
}

__global__ __launch_bounds__(256)
void h_k(const float* __restrict__ bag, const float* __restrict__ Wh,
         const float* __restrict__ bh, float* __restrict__ h)
{
    int wid = threadIdx.x >> 6, lane = threadIdx.x & 63;
    int j = blockIdx.x * 4 + wid;
    const float* wr = Wh + (size_t)j * 512;
    float d = 0.f;
#pragma unroll
    for (int t = 0; t < 2; t++) {
        float4 a = *(const float4*)(wr + t * 256 + lane * 4);
        float4 bv = *(const float4*)(bag + t * 256 + lane * 4);
        d += a.x * bv.x + a.y * bv.y + a.z * bv.z + a.w * bv.w;
    }
#pragma unroll
    for (int o = 32; o; o >>= 1) d += __shfl_xor(d, o);
    if (lane == 0) h[j] = fmaxf(d + bh[j], 0.f);
}

__global__ __launch_bounds__(128)
void logit_k(const float* __restrict__ h, const float* __restrict__ Wc,
             const float* __restrict__ bc, float* __restrict__ out)
{
    int wid = threadIdx.x >> 6, lane = threadIdx.x & 63;
    const float* wr = Wc + (size_t)wid * 512;
    float d = 0.f;
#pragma unroll
    for (int t = 0; t < 2; t++) {
        float4 a = *(const float4*)(wr + t * 256 + lane * 4);
        float4 hv = *(const float4*)(h + t * 256 + lane * 4);
        d += a.x * hv.x + a.y * hv.y + a.z * hv.z + a.w * hv.w;
    }
#pragma unroll
    for (int o = 32; o; o >>= 1) d += __shfl_xor(d, o);
    if (lane == 0) out[wid] = d + bc[wid];
}

extern "C" void kernel_launch(void* const* d_in, const int* in_sizes, int n_in,
                              void* d_out, int out_size, void* d_ws, size_t ws_size,
                              hipStream_t stream)
{
    const float* data    = (const float*)d_in[0];
    const float* protos  = (const float*)d_in[1];
    const float* W_pp    = (const float*)d_in[2];
    const float* b_pp    = (const float*)d_in[3];
    const float* W_cp    = (const float*)d_in[4];
    const float* b_cp    = (const float*)d_in[5];
    const float* sscale  = (const float*)d_in[6];
    const float* enh_w1  = (const float*)d_in[7];
    const float* enh_b1  = (const float*)d_in[8];
    const float* enh_w2  = (const float*)d_in[9];
    const float* enh_b2  = (const float*)d_in[10];
    const float* ln_g    = (const float*)d_in[11];
    const float* ln_b    = (const float*)d_in[12];
    const float* red_w1[3] = {(const float*)d_in[13], (const float*)d_in[17], (const float*)d_in[21]};
    const float* red_b1[3] = {(const float*)d_in[14], (const float*)d_in[18], (const float*)d_in[22]};
    const float* red_w2[3] = {(const float*)d_in[15], (const float*)d_in[19], (const float*)d_in[23]};
    const float* red_b2[3] = {(const float*)d_in[16], (const float*)d_in[20], (const float*)d_in[24]};
    const float* W_proc  = (const float*)d_in[25];
    const float* b_proc  = (const float*)d_in[26];
    const float* g_an    = (const float*)d_in[27];
    const float* b_an    = (const float*)d_in[28];
    const float* W_t     = (const float*)d_in[29];
    const float* b_t     = (const float*)d_in[30];
    const float* W_g     = (const float*)d_in[31];
    const float* b_g     = (const float*)d_in[32];
    const float* W_s     = (const float*)d_in[33];
    const float* b_s     = (const float*)d_in[34];
    const float* W_h     = (const float*)d_in[35];
    const float* b_h     = (const float*)d_in[36];
    const float* W_c     = (const float*)d_in[37];
    const float* b_c     = (const float*)d_in[38];
    float* out = (float*)d_out;

    constexpr int N = 32768, DIN = 768, D = 512;
    constexpr int NCHUNK = 256;
    char* w = (char*)d_ws;
    auto alloc = [&](size_t bytes) -> char* {
        char* p = w; w += (bytes + 255) & ~(size_t)255; return p;
    };
    _Float16* Ph     = (_Float16*)alloc((size_t)N * D * 2);
    _Float16* CTXh   = (_Float16*)alloc((size_t)N * D * 2);
    _Float16* TMPh   = (_Float16*)alloc((size_t)N * D * 2);
    _Float16* Zrawh  = (_Float16*)alloc((size_t)(N + 16) * D * 2);
    _Float16* Zh     = (_Float16*)alloc((size_t)(N + 16) * D * 2);
    _Float16* TGh    = (_Float16*)alloc((size_t)(N + 16) * D * 2);
    _Float16* datah  = (_Float16*)alloc((size_t)N * DIN * 2);
    _Float16* Ah     = (_Float16*)alloc((size_t)N * 128 * 2);
    _Float16* Ch     = (_Float16*)alloc(128 * D * 2);
    _Float16* CTh    = (_Float16*)alloc(128 * D * 2);
    _Float16* Wpph   = (_Float16*)alloc((size_t)D * DIN * 2);
    _Float16* w1h    = (_Float16*)alloc((size_t)3 * D * D * 2);
    _Float16* w2h    = (_Float16*)alloc((size_t)3 * D * D * 2);
    _Float16* Wproch = (_Float16*)alloc((size_t)D * D * 2);
    _Float16* Wth    = (_Float16*)alloc((size_t)D * D * 2);
    _Float16* Wgh    = (_Float16*)alloc((size_t)D * D * 2);
    float*    Psq    = (float*)alloc((size_t)N * 4);
    float*    Csq    = (float*)alloc(128 * 4);
    float*    Ca     = (float*)alloc(128 * D * 4);
    float*    Cb     = (float*)alloc(128 * D * 4);
    float*    H1     = (float*)alloc(128 * D * 4);
    float*    scr    = (float*)alloc((size_t)(N + 16) * 4);
    float*    PB     = (float*)alloc((size_t)NCHUNK * D * 4);
    float*    bag    = (float*)alloc(D * 4);
    float*    hb     = (float*)alloc(D * 4);
    float*    scal   = (float*)alloc(8 * 4);

    dim3 blk(256);
    dim3 blk512(512);
    auto cgrid = [](size_t n) { return dim3((unsigned)((n / 4 + 255) / 256)); };
    auto mgrid = [](int M_, int Nout_) { return dim3((Nout_ + TBN - 1) / TBN, (M_ + TBM - 1) / TBM); };

    // --- convert weights + data to f16 ---
    cvt_k<<<cgrid((size_t)N * DIN), blk, 0, stream>>>(data, datah, N * DIN);
    cvt_k<<<cgrid((size_t)D * DIN), blk, 0, stream>>>(W_pp, Wpph, D * DIN);
    cvt_k<<<cgrid((size_t)3 * D * D), blk, 0, stream>>>(enh_w1, w1h, 3 * D * D);
    cvt_k<<<cgrid((size_t)3 * D * D), blk, 0, stream>>>(enh_w2, w2h, 3 * D * D);
    cvt_k<<<cgrid((size_t)D * D), blk, 0, stream>>>(W_proc, Wproch, D * D);
    cvt_k<<<cgrid((size_t)D * D), blk, 0, stream>>>(W_t, Wth, D * D);
    cvt_k<<<cgrid((size_t)D * D), blk, 0, stream>>>(W_g, Wgh, D * D);

    // P = leaky(data @ W_pp^T + b_pp) -> f16
    mgemm<0, 1, false><<<mgrid(N, D), blk512, 0, stream>>>(datah, Wpph, b_pp, Ph, nullptr, N, DIN, D);
    // C0 = leaky(protos @ W_cp^T + b_cp) -> fp32 (tiny)
    dot_k<1, false><<<dim3(128 * 512 / 4), blk, 0, stream>>>(protos, W_cp, b_cp, Ca, 128, DIN);

    float* C = Ca;
    float* Cn = Cb;
    int Kin = 128;
    for (int i = 0; i < 3; i++) {
        int Kout = Kin >> 1;
        rowsq_k<<<dim3((N + 3) / 4), blk, 0, stream>>>(Ph, Psq, N);
        cvtC_k<<<dim3((Kin * D + 255) / 256), blk, 0, stream>>>(C, Ch, CTh, Kin);
        rowsq_k<<<dim3((Kin + 3) / 4), blk, 0, stream>>>(Ch, Csq, Kin);
        // A = softmax(-dist/denom) fused with S = P@C^T
        simgemm<<<dim3(1, N / TBM), blk512, 0, stream>>>(Ph, Ch, Psq, Csq, sscale, Ah, N, D, Kin);
        // ctx = A @ C -> f16
        mgemm<0, 0, false><<<mgrid(N, D), blk512, 0, stream>>>(Ah, CTh, nullptr, CTXh, nullptr, N, Kin, D);
        // P = LN(P + ctx) -> f16
        ln_k<<<dim3((N + 3) / 4), blk, 0, stream>>>(Ph, CTXh, ln_g + (size_t)i * D, ln_b + (size_t)i * D, Ph, N);
        // enhancer MLP: P += w2 @ relu(w1 @ P + b1) + b2
        mgemm<0, 2, false><<<mgrid(N, D), blk512, 0, stream>>>(Ph, w1h + (size_t)i * D * D, enh_b1 + (size_t)i * D, TMPh, nullptr, N, D, D);
        mgemm<1, 0, false><<<mgrid(N, D), blk512, 0, stream>>>(TMPh, w2h + (size_t)i * D * D, enh_b2 + (size_t)i * D, Ph, nullptr, N, D, D);
        // ProtoReducer (fp32, tiny)
        red1_k<<<dim3(2, Kin), blk, 0, stream>>>(C, red_w1[i], red_b1[i], H1, Kin);
        red2_k<<<dim3(2, Kout), blk, 0, stream>>>(H1, red_w2[i], red_b2[i], Cn, Kin, Kout);
        float* t = C; C = Cn; Cn = t;
        Kin = Kout;
    }

    // Zraw = relu(proc([P; C]))
    mgemm<0, 2, false><<<mgrid(N, D), blk512, 0, stream>>>(Ph, Wproch, b_proc, Zrawh, nullptr, N, D, D);
    dot_k<2, true><<<dim3(16 * 512 / 4), blk, 0, stream>>>(C, W_proc, b_proc, Zrawh + (size_t)N * D, 16, D);
    // Z = LN(Zraw)
    ln_k<<<dim3((N + 16 + 3) / 4), blk, 0, stream>>>(Zrawh, nullptr, g_an, b_an, Zh, N + 16);

    // TG = tanh(Z@W_t^T+b_t) * sigmoid(Z@W_g^T+b_g)  (fused dual GEMM)
    gatgemm<<<mgrid(N + 16, D), blk512, 0, stream>>>(Zh, Wth, Wgh, b_t, b_g, TGh, N + 16, D, D);

    // attention pooling
    score_k<<<dim3((N + 16 + 3) / 4), blk, 0, stream>>>(TGh, W_s, b_s, scr, N + 16);
    pool_k<<<dim3(1), dim3(1024), 0, stream>>>(scr, scal, N + 16);
    int cs = (N + 16 + NCHUNK - 1) / NCHUNK;
    bagp_k<<<dim3(2, NCHUNK), blk, 0, stream>>>(Zh, scr, PB, N + 16, cs);
    bagf_k<<<dim3(2), blk, 0, stream>>>(PB, scal, bag, NCHUNK);

    // classifier head
    h_k<<<dim3(128), blk, 0, stream>>>(bag, W_h, b_h, hb);
    logit_k<<<dim3(1), dim3(128), 0, stream>>>(hb, W_c, b_c, out);
}

// Round 10
// 884.795 us; speedup vs baseline: 1.7761x; 1.0339x over previous
//
#include <hip/hip_runtime.h>
#include <math.h>

typedef _Float16 f16x8 __attribute__((ext_vector_type(8)));
typedef _Float16 f16x4 __attribute__((ext_vector_type(4)));
typedef float f32x4 __attribute__((ext_vector_type(4)));

#define TBM 256
#define TBN 128
#define TBK 32

#define AS1 __attribute__((address_space(1)))
#define AS3 __attribute__((address_space(3)))

__device__ __forceinline__ void gll16(const _Float16* g, _Float16* l)
{
    // direct global->LDS, 16B per lane; LDS dest = wave-uniform base + lane*16
    __builtin_amdgcn_global_load_lds((const AS1 unsigned int*)g,
                                     (AS3 unsigned int*)l, 16, 0, 0);
}

// XCD-aware bijective swizzle of linear block id (nwg % 8 == 0 required for effect)
__device__ __forceinline__ int xcd_swz(int bid, int nwg)
{
    if ((nwg & 7) == 0) {
        int chunk = nwg >> 3;
        bid = (bid & 7) * chunk + (bid >> 3);
    }
    return bid;
}

// ---- fast transcendentals: v_exp_f32 / v_rcp_f32 based (~1e-7 rel err) ----
__device__ __forceinline__ float fsigmoid(float x)
{
    return __builtin_amdgcn_rcpf(1.f + __expf(-x));
}
__device__ __forceinline__ float ftanh(float x)
{
    float ax = fabsf(x);
    float e = __expf(-2.f * ax);
    float t = (1.f - e) * __builtin_amdgcn_rcpf(1.f + e);
    return copysignf(t, x);
}

// ---------------- wave-per-output dot kernel (small-M fp32 GEMMs) ----------------
// ACT: 1 leaky, 2 relu ; F16OUT selects output dtype
template<int ACT, bool F16OUT>
__global__ __launch_bounds__(256)
void dot_k(const float* __restrict__ X, const float* __restrict__ W,
           const float* __restrict__ bias, void* __restrict__ Yv,
           int M, int K)
{
    int gw = (blockIdx.x * 256 + threadIdx.x) >> 6;
    int lane = threadIdx.x & 63;
    if (gw >= M * 512) return;
    int r = gw >> 9, n = gw & 511;
    const float* xr = X + (size_t)r * K;
    const float* wr = W + (size_t)n * K;
    float d = 0.f;
    for (int t = 0; t < K; t += 256) {
        float4 a = *(const float4*)(xr + t + lane * 4);
        float4 b = *(const float4*)(wr + t + lane * 4);
        d += a.x * b.x + a.y * b.y + a.z * b.z + a.w * b.w;
    }
#pragma unroll
    for (int o = 32; o; o >>= 1) d += __shfl_xor(d, o);
    if (lane == 0) {
        float v = d + bias[n];
        if (ACT == 1) v = v > 0.f ? v : 0.01f * v;
        else if (ACT == 2) v = fmaxf(v, 0.f);
        if (F16OUT) ((_Float16*)Yv)[(size_t)r * 512 + n] = (_Float16)v;
        else        ((float*)Yv)[(size_t)r * 512 + n] = v;
    }
}

// ---------------- f16 MFMA GEMM: 256x128 tile, 8 waves, LDS dbuf ----------------
// v[m,n] = sum_k A[m,k]*B[n,k] + bias[n]
// MODE 0: out = act(v) -> Yh f16 (or Yf fp32 if F32OUT); MODE 1: out = Yh + v
// ACT: 0 none, 1 leaky, 2 relu
template<int MODE, int ACT, bool F32OUT>
__global__ __launch_bounds__(512)
void mgemm(const _Float16* __restrict__ A, const _Float16* __restrict__ B,
           const float* __restrict__ bias, _Float16* __restrict__ Yh,
           float* __restrict__ Yf, int M, int K, int Nout)
{
    __shared__ _Float16 As[2][TBM * TBK];   // 16 KB each
    __shared__ _Float16 Bs[2][TBN * TBK];   // 8 KB each
    const int tid = threadIdx.x;
    const int lane = tid & 63;
    const int wid = tid >> 6;               // 0..7
    const int wr = wid >> 1, wc = wid & 1;  // 4 x 2 wave grid

    int bid = xcd_swz(blockIdx.y * gridDim.x + blockIdx.x, gridDim.x * gridDim.y);
    const int m0 = (bid / gridDim.x) * TBM;
    const int n0 = (bid % gridDim.x) * TBN;

    f32x4 acc[4][4] = {};
    const int nt = K / TBK;

    const int lrow = lane >> 2;          // 0..15 row within chunk
    const int lk = (lane & 3) * 8;       // f16 offset within 32-elem k slab

    auto stage = [&](int t, int buf) {   // 3 gll per thread
        const int k0 = t * TBK;
#pragma unroll
        for (int q = 0; q < 2; q++) {
            int c = wid * 2 + q;                      // 0..15 (A chunks)
            int r = c * 16 + lrow;
            int am = min(m0 + r, M - 1);
            gll16(A + (size_t)am * K + k0 + lk, &As[buf][c * 512]);
        }
        {
            int c = wid;                              // 0..7 (B chunks)
            int r = c * 16 + lrow;
            int bn = min(n0 + r, Nout - 1);
            gll16(B + (size_t)bn * K + k0 + lk, &Bs[buf][c * 512]);
        }
    };

    stage(0, 0);
    __syncthreads();
    for (int t = 0; t < nt; ++t) {
        const int cur = t & 1;
        if (t + 1 < nt) stage(t + 1, cur ^ 1);
        f16x8 af[4], bf[4];
#pragma unroll
        for (int mi = 0; mi < 4; mi++)
            af[mi] = *(const f16x8*)(&As[cur][(wr * 64 + mi * 16 + (lane & 15)) * TBK + (lane >> 4) * 8]);
#pragma unroll
        for (int nj = 0; nj < 4; nj++)
            bf[nj] = *(const f16x8*)(&Bs[cur][(wc * 64 + nj * 16 + (lane & 15)) * TBK + (lane >> 4) * 8]);
#pragma unroll
        for (int mi = 0; mi < 4; mi++)
#pragma unroll
            for (int nj = 0; nj < 4; nj++)
                acc[mi][nj] = __builtin_amdgcn_mfma_f32_16x16x32_f16(af[mi], bf[nj], acc[mi][nj], 0, 0, 0);
        __syncthreads();
    }

#pragma unroll
    for (int mi = 0; mi < 4; mi++) {
        int mbase = m0 + wr * 64 + mi * 16 + (lane >> 4) * 4;
#pragma unroll
        for (int nj = 0; nj < 4; nj++) {
            int n = n0 + wc * 64 + nj * 16 + (lane & 15);
            if (n < Nout) {
                float bv = bias ? bias[n] : 0.f;
#pragma unroll
                for (int r = 0; r < 4; r++) {
                    int m = mbase + r;
                    if (m < M) {
                        float v = acc[mi][nj][r] + bv;
                        size_t idx = (size_t)m * Nout + n;
                        if (MODE == 0) {
                            if (ACT == 1) v = v > 0.f ? v : 0.01f * v;
                            else if (ACT == 2) v = fmaxf(v, 0.f);
                            if (F32OUT) Yf[idx] = v;
                            else        Yh[idx] = (_Float16)v;
                        } else {
                            float s = (float)Yh[idx] + v;
                            Yh[idx] = (_Float16)s;
                        }
                    }
                }
            }
        }
    }
}

// ---------------- fused dual gate GEMM: 256x128 tile, 8 waves ----------------
__global__ __launch_bounds__(512)
void gatgemm(const _Float16* __restrict__ A, const _Float16* __restrict__ B1,
             const _Float16* __restrict__ B2, const float* __restrict__ c1,
             const float* __restrict__ c2, _Float16* __restrict__ Y,
             int M, int K, int Nout)
{
    __shared__ _Float16 As[2][TBM * TBK];
    __shared__ _Float16 B1s[2][TBN * TBK];
    __shared__ _Float16 B2s[2][TBN * TBK];
    const int tid = threadIdx.x;
    const int lane = tid & 63;
    const int wid = tid >> 6;
    const int wr = wid >> 1, wc = wid & 1;

    int bid = xcd_swz(blockIdx.y * gridDim.x + blockIdx.x, gridDim.x * gridDim.y);
    const int m0 = (bid / gridDim.x) * TBM;
    const int n0 = (bid % gridDim.x) * TBN;

    f32x4 acc1[4][4] = {};
    f32x4 acc2[4][4] = {};
    const int nt = K / TBK;

    const int lrow = lane >> 2;
    const int lk = (lane & 3) * 8;

    auto stage = [&](int t, int buf) {   // 4 gll per thread
        const int k0 = t * TBK;
#pragma unroll
        for (int q = 0; q < 2; q++) {
            int c = wid * 2 + q;
            int r = c * 16 + lrow;
            int am = min(m0 + r, M - 1);
            gll16(A + (size_t)am * K + k0 + lk, &As[buf][c * 512]);
        }
        {
            int c = wid;
            int r = c * 16 + lrow;
            int bn = min(n0 + r, Nout - 1);
            gll16(B1 + (size_t)bn * K + k0 + lk, &B1s[buf][c * 512]);
            gll16(B2 + (size_t)bn * K + k0 + lk, &B2s[buf][c * 512]);
        }
    };

    stage(0, 0);
    __syncthreads();
    for (int t = 0; t < nt; ++t) {
        const int cur = t & 1;
        if (t + 1 < nt) stage(t + 1, cur ^ 1);
        f16x8 af[4], bf1[4], bf2[4];
#pragma unroll
        for (int mi = 0; mi < 4; mi++)
            af[mi] = *(const f16x8*)(&As[cur][(wr * 64 + mi * 16 + (lane & 15)) * TBK + (lane >> 4) * 8]);
#pragma unroll
        for (int nj = 0; nj < 4; nj++) {
            int ro = (wc * 64 + nj * 16 + (lane & 15)) * TBK + (lane >> 4) * 8;
            bf1[nj] = *(const f16x8*)(&B1s[cur][ro]);
            bf2[nj] = *(const f16x8*)(&B2s[cur][ro]);
        }
#pragma unroll
        for (int mi = 0; mi < 4; mi++)
#pragma unroll
            for (int nj = 0; nj < 4; nj++) {
                acc1[mi][nj] = __builtin_amdgcn_mfma_f32_16x16x32_f16(af[mi], bf1[nj], acc1[mi][nj], 0, 0, 0);
                acc2[mi][nj] = __builtin_amdgcn_mfma_f32_16x16x32_f16(af[mi], bf2[nj], acc2[mi][nj], 0, 0, 0);
            }
        __syncthreads();
    }

#pragma unroll
    for (int mi = 0; mi < 4; mi++) {
        int mbase = m0 + wr * 64 + mi * 16 + (lane >> 4) * 4;
#pragma unroll
        for (int nj = 0; nj < 4; nj++) {
            int n = n0 + wc * 64 + nj * 16 + (lane & 15);
            if (n < Nout) {
                float bv1 = c1[n], bv2 = c2[n];
#pragma unroll
                for (int r = 0; r < 4; r++) {
                    int m = mbase + r;
                    if (m < M) {
                        float t1 = ftanh(acc1[mi][nj][r] + bv1);
                        float g1 = fsigmoid(acc2[mi][nj][r] + bv2);
                        Y[(size_t)m * Nout + n] = (_Float16)(t1 * g1);
                    }
                }
            }
        }
    }
}

// ---------------- fused sim GEMM + row softmax: 128-row blocks, 4 waves ----------------
// S = P@C^T ; sim = -sqrt(max(pp+cc-2S,1e-12))/denom ; Ah = softmax_row(sim) f16
#define SBM 128
__global__ __launch_bounds__(256)
void simgemm(const _Float16* __restrict__ A, const _Float16* __restrict__ B,
             const float* __restrict__ Psq, const float* __restrict__ Csq,
             const float* __restrict__ sscale, _Float16* __restrict__ Ah,
             int M, int K, int Kin)
{
    __shared__ _Float16 As[2][SBM * TBK];
    __shared__ _Float16 Bs[2][SBM * TBK];
    __shared__ float redmx[2][SBM];
    __shared__ float redsm[2][SBM];
    const int tid = threadIdx.x;
    const int lane = tid & 63;
    const int wid = tid >> 6;
    const int wr = wid >> 1, wc = wid & 1;
    const int m0 = blockIdx.y * SBM;

    f32x4 acc[4][4] = {};
    const int nt = K / TBK;
    const int lrow = lane >> 2;
    const int lk = (lane & 3) * 8;

    auto stage = [&](int t, int buf) {   // 4 gll per thread
        const int k0 = t * TBK;
#pragma unroll
        for (int q = 0; q < 2; q++) {
            int c = wid * 2 + q;          // 0..7
            int r = c * 16 + lrow;
            int am = min(m0 + r, M - 1);
            int bn = min(r, Kin - 1);
            gll16(A + (size_t)am * K + k0 + lk, &As[buf][c * 512]);
            gll16(B + (size_t)bn * K + k0 + lk, &Bs[buf][c * 512]);
        }
    };

    stage(0, 0);
    __syncthreads();
    for (int t = 0; t < nt; ++t) {
        const int cur = t & 1;
        if (t + 1 < nt) stage(t + 1, cur ^ 1);
        f16x8 af[4], bf[4];
#pragma unroll
        for (int mi = 0; mi < 4; mi++)
            af[mi] = *(const f16x8*)(&As[cur][(wr * 64 + mi * 16 + (lane & 15)) * TBK + (lane >> 4) * 8]);
#pragma unroll
        for (int nj = 0; nj < 4; nj++)
            bf[nj] = *(const f16x8*)(&Bs[cur][(wc * 64 + nj * 16 + (lane & 15)) * TBK + (lane >> 4) * 8]);
#pragma unroll
        for (int mi = 0; mi < 4; mi++)
#pragma unroll
            for (int nj = 0; nj < 4; nj++)
                acc[mi][nj] = __builtin_amdgcn_mfma_f32_16x16x32_f16(af[mi], bf[nj], acc[mi][nj], 0, 0, 0);
        __syncthreads();
    }

    const float denom = fmaxf(1e-6f, sscale[0]);
    const int colbase = wc * 64 + (lane & 15);
    const int g = lane >> 4;
    float cc[4];
#pragma unroll
    for (int nj = 0; nj < 4; nj++) {
        int n = colbase + nj * 16;
        cc[nj] = (n < Kin) ? Csq[n] : 0.f;
    }

    // pass 1: sim values into acc, per-row max -> LDS
#pragma unroll
    for (int mi = 0; mi < 4; mi++) {
#pragma unroll
        for (int r = 0; r < 4; r++) {
            int row = wr * 64 + mi * 16 + g * 4 + r;
            float pp = Psq[m0 + row];
            float mx = -INFINITY;
#pragma unroll
            for (int nj = 0; nj < 4; nj++) {
                int n = colbase + nj * 16;
                float v = -INFINITY;
                if (n < Kin)
                    v = -sqrtf(fmaxf(pp + cc[nj] - 2.f * acc[mi][nj][r], 1e-12f)) / denom;
                acc[mi][nj][r] = v;
                mx = fmaxf(mx, v);
            }
#pragma unroll
            for (int o = 1; o < 16; o <<= 1) mx = fmaxf(mx, __shfl_xor(mx, o));
            if ((lane & 15) == 0) redmx[wc][row] = mx;
        }
    }
    __syncthreads();

    // pass 2: exp + per-row sum -> LDS
#pragma unroll
    for (int mi = 0; mi < 4; mi++) {
#pragma unroll
        for (int r = 0; r < 4; r++) {
            int row = wr * 64 + mi * 16 + g * 4 + r;
            float mx = fmaxf(redmx[0][row], redmx[1][row]);
            float s = 0.f;
#pragma unroll
            for (int nj = 0; nj < 4; nj++) {
                int n = colbase + nj * 16;
                float e = (n < Kin) ? __expf(acc[mi][nj][r] - mx) : 0.f;
                acc[mi][nj][r] = e;
                s += e;
            }
#pragma unroll
            for (int o = 1; o < 16; o <<= 1) s += __shfl_xor(s, o);
            if ((lane & 15) == 0) redsm[wc][row] = s;
        }
    }
    __syncthreads();

    // pass 3: normalize + write f16
#pragma unroll
    for (int mi = 0; mi < 4; mi++) {
#pragma unroll
        for (int r = 0; r < 4; r++) {
            int row = wr * 64 + mi * 16 + g * 4 + r;
            float inv = __builtin_amdgcn_rcpf(redsm[0][row] + redsm[1][row]);
            int m = m0 + row;
#pragma unroll
            for (int nj = 0; nj < 4; nj++) {
                int n = colbase + nj * 16;
                if (n < Kin)
                    Ah[(size_t)m * Kin + n] = (_Float16)(acc[mi][nj][r] * inv);
            }
        }
    }
}

// ---------------- converters ----------------
__global__ __launch_bounds__(256)
void cvt_k(const float* __restrict__ x, _Float16* __restrict__ y, int n)
{
    int i = (blockIdx.x * 256 + threadIdx.x) * 4;
    if (i < n) {
        float4 v = *(const float4*)(x + i);
        f16x4 h = { (_Float16)v.x, (_Float16)v.y, (_Float16)v.z, (_Float16)v.w };
        *(f16x4*)(y + i) = h;
    }
}

// C [Kin,512] fp32 -> Ch [Kin,512] f16 and CTh [512,Kin] f16
__global__ __launch_bounds__(256)
void cvtC_k(const float* __restrict__ C, _Float16* __restrict__ Ch,
            _Float16* __restrict__ CTh, int Kin)
{
    int i = blockIdx.x * 256 + threadIdx.x;
    if (i < Kin * 512) {
        int j = i >> 9, d = i & 511;
        float v = C[i];
        Ch[i] = (_Float16)v;
        CTh[d * Kin + j] = (_Float16)v;
    }
}

// ---------------- small kernels (f16 activations) ----------------
__global__ __launch_bounds__(256)
void rowsq_k(const _Float16* __restrict__ X, float* __restrict__ out, int M)
{
    int wid = threadIdx.x >> 6, lane = threadIdx.x & 63;
    int row = blockIdx.x * 4 + wid;
    if (row >= M) return;
    f16x8 a = *(const f16x8*)(X + (size_t)row * 512 + lane * 8);
    float s = 0.f;
#pragma unroll
    for (int q = 0; q < 8; q++) { float f = (float)a[q]; s += f * f; }
#pragma unroll
    for (int o = 32; o; o >>= 1) s += __shfl_xor(s, o);
    if (lane == 0) out[row] = s;
}

// Yh = LN(X (+R)) * g + b, f16 in/out, fp32 math; one wave per row
__global__ __launch_bounds__(256)
void ln_k(const _Float16* __restrict__ X, const _Float16* __restrict__ R,
          const float* __restrict__ g, const float* __restrict__ b,
          _Float16* __restrict__ Yh, int M)
{
    int wid = threadIdx.x >> 6, lane = threadIdx.x & 63;
    int row = blockIdx.x * 4 + wid;
    if (row >= M) return;
    f16x8 a = *(const f16x8*)(X + (size_t)row * 512 + lane * 8);
    float v[8];
#pragma unroll
    for (int q = 0; q < 8; q++) v[q] = (float)a[q];
    if (R) {
        f16x8 c = *(const f16x8*)(R + (size_t)row * 512 + lane * 8);
#pragma unroll
        for (int q = 0; q < 8; q++) v[q] += (float)c[q];
    }
    float s = 0.f, ss = 0.f;
#pragma unroll
    for (int q = 0; q < 8; q++) { s += v[q]; ss += v[q] * v[q]; }
#pragma unroll
    for (int o = 32; o; o >>= 1) { s += __shfl_xor(s, o); ss += __shfl_xor(ss, o); }
    float mean = s * (1.f / 512.f);
    float var = ss * (1.f / 512.f) - mean * mean;
    float inv = 1.f / sqrtf(var + 1e-5f);
    int d0 = lane * 8;
    f16x8 o8;
#pragma unroll
    for (int q = 0; q < 8; q++)
        o8[q] = (_Float16)((v[q] - mean) * inv * g[d0 + q] + b[d0 + q]);
    *(f16x8*)(Yh + (size_t)row * 512 + d0) = o8;
}

__global__ __launch_bounds__(256)
void red1_k(const float* __restrict__ C, const float* __restrict__ w1,
            const float* __restrict__ b1, float* __restrict__ H1, int Kin)
{
    int d = blockIdx.x * 256 + threadIdx.x;
    int j = blockIdx.y;
    float acc = b1[j];
    for (int k = 0; k < Kin; k++) acc = fmaf(C[(size_t)k * 512 + d], w1[(size_t)j * Kin + k], acc);
    H1[(size_t)j * 512 + d] = fmaxf(acc, 0.f);
}

__global__ __launch_bounds__(256)
void red2_k(const float* __restrict__ H1, const float* __restrict__ w2,
            const float* __restrict__ b2, float* __restrict__ Cn, int Kin, int Kout)
{
    int d = blockIdx.x * 256 + threadIdx.x;
    int j2 = blockIdx.y;
    float acc = b2[j2];
    for (int j = 0; j < Kin; j++) acc = fmaf(H1[(size_t)j * 512 + d], w2[(size_t)j2 * Kin + j], acc);
    Cn[(size_t)j2 * 512 + d] = acc;
}

// scores[i] = dot(TG[i,:], Ws) + bs; TG f16
__global__ __launch_bounds__(256)
void score_k(const _Float16* __restrict__ TG, const float* __restrict__ Ws,
             const float* __restrict__ bs, float* __restrict__ out, int M)
{
    int wid = threadIdx.x >> 6, lane = threadIdx.x & 63;
    int row = blockIdx.x * 4 + wid;
    if (row >= M) return;
    f16x8 a = *(const f16x8*)(TG + (size_t)row * 512 + lane * 8);
    float4 w0 = *(const float4*)(Ws + lane * 8);
    float4 w1 = *(const float4*)(Ws + lane * 8 + 4);
    float d = (float)a[0] * w0.x + (float)a[1] * w0.y + (float)a[2] * w0.z + (float)a[3] * w0.w
            + (float)a[4] * w1.x + (float)a[5] * w1.y + (float)a[6] * w1.z + (float)a[7] * w1.w;
#pragma unroll
    for (int o = 32; o; o >>= 1) d += __shfl_xor(d, o);
    if (lane == 0) out[row] = d + bs[0];
}

__global__ __launch_bounds__(1024)
void pool_k(float* __restrict__ s, float* __restrict__ scal, int M)
{
    __shared__ float sm[16];
    int tid = threadIdx.x, lane = tid & 63, wid = tid >> 6;
    float mx = -INFINITY;
    for (int i = tid * 4; i < M; i += 4096) {
        float4 a = *(const float4*)(s + i);
        mx = fmaxf(fmaxf(fmaxf(mx, a.x), fmaxf(a.y, a.z)), a.w);
    }
#pragma unroll
    for (int o = 32; o; o >>= 1) mx = fmaxf(mx, __shfl_xor(mx, o));
    if (lane == 0) sm[wid] = mx;
    __syncthreads();
    if (wid == 0) {
        float v = (lane < 16) ? sm[lane] : -INFINITY;
#pragma unroll
        for (int o = 8; o; o >>= 1) v = fmaxf(v, __shfl_xor(v, o));
        if (lane == 0) sm[0] = v;
    }
    __syncthreads();
    float gmax = sm[0];
    __syncthreads();
    float sum = 0.f;
    for (int i = tid * 4; i < M; i += 4096) {
        float4 a = *(const float4*)(s + i);
        float4 e;
        e.x = __expf(a.x - gmax); e.y = __expf(a.y - gmax);
        e.z = __expf(a.z - gmax); e.w = __expf(a.w - gmax);
        *(float4*)(s + i) = e;
        sum += e.x + e.y + e.z + e.w;
    }
#pragma unroll
    for (int o = 32; o; o >>= 1) sum += __shfl_xor(sum, o);
    if (lane == 0) sm[wid] = sum;
    __syncthreads();
    if (tid == 0) {
        float t = 0.f;
        for (int w = 0; w < 16; w++) t += sm[w];
        scal[0] = t;
    }
}

__global__ __launch_bounds__(256)
void bagp_k(const _Float16* __restrict__ Z, const float* __restrict__ w,
            float* __restrict__ PB, int M, int cs)
{
    int d = blockIdx.x * 256 + threadIdx.x;
    int chunk = blockIdx.y;
    int i0 = chunk * cs;
    int i1 = min(M, i0 + cs);
    float acc = 0.f;
    for (int i = i0; i < i1; i++) acc = fmaf(w[i], (float)Z[(size_t)i * 512 + d], acc);
    PB[(size_t)chunk * 512 + d] = acc;
}

__global__ __launch_bounds__(256)
void bagf_k(const float* __restrict__ PB, const float* __restrict__ scal,
            float* __restrict__ bag, int nchunk)
{
    int d = blockIdx.x * 256 + threadIdx.x;
    float acc = 0.f;
    for (int c = 0; c < nchunk; c++) acc += PB[(size_t)c * 512 + d];
    bag[d] = acc / scal[0];
}

__global__ __launch_bounds__(256)
void h_k(const float* __restrict__ bag, const float* __restrict__ Wh,
         const float* __restrict__ bh, float* __restrict__ h)
{
    int wid = threadIdx.x >> 6, lane = threadIdx.x & 63;
    int j = blockIdx.x * 4 + wid;
    const float* wr = Wh + (size_t)j * 512;
    float d = 0.f;
#pragma unroll
    for (int t = 0; t < 2; t++) {
        float4 a = *(const float4*)(wr + t * 256 + lane * 4);
        float4 bv = *(const float4*)(bag + t * 256 + lane * 4);
        d += a.x * bv.x + a.y * bv.y + a.z * bv.z + a.w * bv.w;
    }
#pragma unroll
    for (int o = 32; o; o >>= 1) d += __shfl_xor(d, o);
    if (lane == 0) h[j] = fmaxf(d + bh[j], 0.f);
}

__global__ __launch_bounds__(128)
void logit_k(const float* __restrict__ h, const float* __restrict__ Wc,
             const float* __restrict__ bc, float* __restrict__ out)
{
    int wid = threadIdx.x >> 6, lane = threadIdx.x & 63;
    const float* wr = Wc + (size_t)wid * 512;
    float d = 0.f;
#pragma unroll
    for (int t = 0; t < 2; t++) {
        float4 a = *(const float4*)(wr + t * 256 + lane * 4);
        float4 hv = *(const float4*)(h + t * 256 + lane * 4);
        d += a.x * hv.x + a.y * hv.y + a.z * hv.z + a.w * hv.w;
    }
#pragma unroll
    for (int o = 32; o; o >>= 1) d += __shfl_xor(d, o);
    if (lane == 0) out[wid] = d + bc[wid];
}

extern "C" void kernel_launch(void* const* d_in, const int* in_sizes, int n_in,
                              void* d_out, int out_size, void* d_ws, size_t ws_size,
                              hipStream_t stream)
{
    const float* data    = (const float*)d_in[0];
    const float* protos  = (const float*)d_in[1];
    const float* W_pp    = (const float*)d_in[2];
    const float* b_pp    = (const float*)d_in[3];
    const float* W_cp    = (const float*)d_in[4];
    const float* b_cp    = (const float*)d_in[5];
    const float* sscale  = (const float*)d_in[6];
    const float* enh_w1  = (const float*)d_in[7];
    const float* enh_b1  = (const float*)d_in[8];
    const float* enh_w2  = (const float*)d_in[9];
    const float* enh_b2  = (const float*)d_in[10];
    const float* ln_g    = (const float*)d_in[11];
    const float* ln_b    = (const float*)d_in[12];
    const float* red_w1[3] = {(const float*)d_in[13], (const float*)d_in[17], (const float*)d_in[21]};
    const float* red_b1[3] = {(const float*)d_in[14], (const float*)d_in[18], (const float*)d_in[22]};
    const float* red_w2[3] = {(const float*)d_in[15], (const float*)d_in[19], (const float*)d_in[23]};
    const float* red_b2[3] = {(const float*)d_in[16], (const float*)d_in[20], (const float*)d_in[24]};
    const float* W_proc  = (const float*)d_in[25];
    const float* b_proc  = (const float*)d_in[26];
    const float* g_an    = (const float*)d_in[27];
    const float* b_an    = (const float*)d_in[28];
    const float* W_t     = (const float*)d_in[29];
    const float* b_t     = (const float*)d_in[30];
    const float* W_g     = (const float*)d_in[31];
    const float* b_g     = (const float*)d_in[32];
    const float* W_s     = (const float*)d_in[33];
    const float* b_s     = (const float*)d_in[34];
    const float* W_h     = (const float*)d_in[35];
    const float* b_h     = (const float*)d_in[36];
    const float* W_c     = (const float*)d_in[37];
    const float* b_c     = (const float*)d_in[38];
    float* out = (float*)d_out;

    constexpr int N = 32768, DIN = 768, D = 512;
    constexpr int NCHUNK = 256;
    char* w = (char*)d_ws;
    auto alloc = [&](size_t bytes) -> char* {
        char* p = w; w += (bytes + 255) & ~(size_t)255; return p;
    };
    _Float16* Ph     = (_Float16*)alloc((size_t)N * D * 2);
    _Float16* CTXh   = (_Float16*)alloc((size_t)N * D * 2);
    _Float16* TMPh   = (_Float16*)alloc((size_t)N * D * 2);
    _Float16* Zrawh  = (_Float16*)alloc((size_t)(N + 16) * D * 2);
    _Float16* Zh     = (_Float16*)alloc((size_t)(N + 16) * D * 2);
    _Float16* TGh    = (_Float16*)alloc((size_t)(N + 16) * D * 2);
    _Float16* datah  = (_Float16*)alloc((size_t)N * DIN * 2);
    _Float16* Ah     = (_Float16*)alloc((size_t)N * 128 * 2);
    _Float16* Ch     = (_Float16*)alloc(128 * D * 2);
    _Float16* CTh    = (_Float16*)alloc(128 * D * 2);
    _Float16* Wpph   = (_Float16*)alloc((size_t)D * DIN * 2);
    _Float16* w1h    = (_Float16*)alloc((size_t)3 * D * D * 2);
    _Float16* w2h    = (_Float16*)alloc((size_t)3 * D * D * 2);
    _Float16* Wproch = (_Float16*)alloc((size_t)D * D * 2);
    _Float16* Wth    = (_Float16*)alloc((size_t)D * D * 2);
    _Float16* Wgh    = (_Float16*)alloc((size_t)D * D * 2);
    float*    Psq    = (float*)alloc((size_t)N * 4);
    float*    Csq    = (float*)alloc(128 * 4);
    float*    Ca     = (float*)alloc(128 * D * 4);
    float*    Cb     = (float*)alloc(128 * D * 4);
    float*    H1     = (float*)alloc(128 * D * 4);
    float*    scr    = (float*)alloc((size_t)(N + 16) * 4);
    float*    PB     = (float*)alloc((size_t)NCHUNK * D * 4);
    float*    bag    = (float*)alloc(D * 4);
    float*    hb     = (float*)alloc(D * 4);
    float*    scal   = (float*)alloc(8 * 4);

    dim3 blk(256);
    dim3 blk512(512);
    auto cgrid = [](size_t n) { return dim3((unsigned)((n / 4 + 255) / 256)); };
    auto mgrid = [](int M_, int Nout_) { return dim3((Nout_ + TBN - 1) / TBN, (M_ + TBM - 1) / TBM); };

    // --- convert weights + data to f16 ---
    cvt_k<<<cgrid((size_t)N * DIN), blk, 0, stream>>>(data, datah, N * DIN);
    cvt_k<<<cgrid((size_t)D * DIN), blk, 0, stream>>>(W_pp, Wpph, D * DIN);
    cvt_k<<<cgrid((size_t)3 * D * D), blk, 0, stream>>>(enh_w1, w1h, 3 * D * D);
    cvt_k<<<cgrid((size_t)3 * D * D), blk, 0, stream>>>(enh_w2, w2h, 3 * D * D);
    cvt_k<<<cgrid((size_t)D * D), blk, 0, stream>>>(W_proc, Wproch, D * D);
    cvt_k<<<cgrid((size_t)D * D), blk, 0, stream>>>(W_t, Wth, D * D);
    cvt_k<<<cgrid((size_t)D * D), blk, 0, stream>>>(W_g, Wgh, D * D);

    // P = leaky(data @ W_pp^T + b_pp) -> f16
    mgemm<0, 1, false><<<mgrid(N, D), blk512, 0, stream>>>(datah, Wpph, b_pp, Ph, nullptr, N, DIN, D);
    // C0 = leaky(protos @ W_cp^T + b_cp) -> fp32 (tiny)
    dot_k<1, false><<<dim3(128 * 512 / 4), blk, 0, stream>>>(protos, W_cp, b_cp, Ca, 128, DIN);

    float* C = Ca;
    float* Cn = Cb;
    int Kin = 128;
    for (int i = 0; i < 3; i++) {
        int Kout = Kin >> 1;
        rowsq_k<<<dim3((N + 3) / 4), blk, 0, stream>>>(Ph, Psq, N);
        cvtC_k<<<dim3((Kin * D + 255) / 256), blk, 0, stream>>>(C, Ch, CTh, Kin);
        rowsq_k<<<dim3((Kin + 3) / 4), blk, 0, stream>>>(Ch, Csq, Kin);
        // A = softmax(-dist/denom) fused with S = P@C^T
        simgemm<<<dim3(1, N / SBM), blk, 0, stream>>>(Ph, Ch, Psq, Csq, sscale, Ah, N, D, Kin);
        // ctx = A @ C -> f16
        mgemm<0, 0, false><<<mgrid(N, D), blk512, 0, stream>>>(Ah, CTh, nullptr, CTXh, nullptr, N, Kin, D);
        // P = LN(P + ctx) -> f16
        ln_k<<<dim3((N + 3) / 4), blk, 0, stream>>>(Ph, CTXh, ln_g + (size_t)i * D, ln_b + (size_t)i * D, Ph, N);
        // enhancer MLP: P += w2 @ relu(w1 @ P + b1) + b2
        mgemm<0, 2, false><<<mgrid(N, D), blk512, 0, stream>>>(Ph, w1h + (size_t)i * D * D, enh_b1 + (size_t)i * D, TMPh, nullptr, N, D, D);
        mgemm<1, 0, false><<<mgrid(N, D), blk512, 0, stream>>>(TMPh, w2h + (size_t)i * D * D, enh_b2 + (size_t)i * D, Ph, nullptr, N, D, D);
        // ProtoReducer (fp32, tiny)
        red1_k<<<dim3(2, Kin), blk, 0, stream>>>(C, red_w1[i], red_b1[i], H1, Kin);
        red2_k<<<dim3(2, Kout), blk, 0, stream>>>(H1, red_w2[i], red_b2[i], Cn, Kin, Kout);
        float* t = C; C = Cn; Cn = t;
        Kin = Kout;
    }

    // Zraw = relu(proc([P; C]))
    mgemm<0, 2, false><<<mgrid(N, D), blk512, 0, stream>>>(Ph, Wproch, b_proc, Zrawh, nullptr, N, D, D);
    dot_k<2, true><<<dim3(16 * 512 / 4), blk, 0, stream>>>(C, W_proc, b_proc, Zrawh + (size_t)N * D, 16, D);
    // Z = LN(Zraw)
    ln_k<<<dim3((N + 16 + 3) / 4), blk, 0, stream>>>(Zrawh, nullptr, g_an, b_an, Zh, N + 16);

    // TG = tanh(Z@W_t^T+b_t) * sigmoid(Z@W_g^T+b_g)  (fused dual GEMM)
    gatgemm<<<mgrid(N + 16, D), blk512, 0, stream>>>(Zh, Wth, Wgh, b_t, b_g, TGh, N + 16, D, D);

    // attention pooling
    score_k<<<dim3((N + 16 + 3) / 4), blk, 0, stream>>>(TGh, W_s, b_s, scr, N + 16);
    pool_k<<<dim3(1), dim3(1024), 0, stream>>>(scr, scal, N + 16);
    int cs = (N + 16 + NCHUNK - 1) / NCHUNK;
    bagp_k<<<dim3(2, NCHUNK), blk, 0, stream>>>(Zh, scr, PB, N + 16, cs);
    bagf_k<<<dim3(2), blk, 0, stream>>>(PB, scal, bag, NCHUNK);

    // classifier head
    h_k<<<dim3(128), blk, 0, stream>>>(bag, W_h, b_h, hb);
    logit_k<<<dim3(1), dim3(128), 0, stream>>>(hb, W_c, b_c, out);
}

// Round 11
// 864.537 us; speedup vs baseline: 1.8177x; 1.0234x over previous
//
#include <hip/hip_runtime.h>
#include <math.h>

typedef _Float16 f16x8 __attribute__((ext_vector_type(8)));
typedef _Float16 f16x4 __attribute__((ext_vector_type(4)));
typedef float f32x4 __attribute__((ext_vector_type(4)));

#define TBM 256
#define TBN 128
#define TBK 32

#define AS1 __attribute__((address_space(1)))
#define AS3 __attribute__((address_space(3)))

__device__ __forceinline__ void gll16(const _Float16* g, _Float16* l)
{
    // direct global->LDS, 16B per lane; LDS dest = wave-uniform base + lane*16
    __builtin_amdgcn_global_load_lds((const AS1 unsigned int*)g,
                                     (AS3 unsigned int*)l, 16, 0, 0);
}

// XCD-aware bijective swizzle of linear block id (nwg % 8 == 0 required for effect)
__device__ __forceinline__ int xcd_swz(int bid, int nwg)
{
    if ((nwg & 7) == 0) {
        int chunk = nwg >> 3;
        bid = (bid & 7) * chunk + (bid >> 3);
    }
    return bid;
}

// ---- fast transcendentals: v_exp_f32 / v_rcp_f32 based (~1e-7 rel err) ----
__device__ __forceinline__ float fsigmoid(float x)
{
    return __builtin_amdgcn_rcpf(1.f + __expf(-x));
}
__device__ __forceinline__ float ftanh(float x)
{
    float ax = fabsf(x);
    float e = __expf(-2.f * ax);
    float t = (1.f - e) * __builtin_amdgcn_rcpf(1.f + e);
    return copysignf(t, x);
}

// ---------------- wave-per-output dot kernel (small-M fp32 GEMMs) ----------------
// ACT: 1 leaky, 2 relu ; F16OUT selects output dtype
template<int ACT, bool F16OUT>
__global__ __launch_bounds__(256)
void dot_k(const float* __restrict__ X, const float* __restrict__ W,
           const float* __restrict__ bias, void* __restrict__ Yv,
           int M, int K)
{
    int gw = (blockIdx.x * 256 + threadIdx.x) >> 6;
    int lane = threadIdx.x & 63;
    if (gw >= M * 512) return;
    int r = gw >> 9, n = gw & 511;
    const float* xr = X + (size_t)r * K;
    const float* wr = W + (size_t)n * K;
    float d = 0.f;
    for (int t = 0; t < K; t += 256) {
        float4 a = *(const float4*)(xr + t + lane * 4);
        float4 b = *(const float4*)(wr + t + lane * 4);
        d += a.x * b.x + a.y * b.y + a.z * b.z + a.w * b.w;
    }
#pragma unroll
    for (int o = 32; o; o >>= 1) d += __shfl_xor(d, o);
    if (lane == 0) {
        float v = d + bias[n];
        if (ACT == 1) v = v > 0.f ? v : 0.01f * v;
        else if (ACT == 2) v = fmaxf(v, 0.f);
        if (F16OUT) ((_Float16*)Yv)[(size_t)r * 512 + n] = (_Float16)v;
        else        ((float*)Yv)[(size_t)r * 512 + n] = v;
    }
}

// ---------------- f16 MFMA GEMM: 256x128 tile, 8 waves, LDS dbuf, repacked epilogue ----------------
// v[m,n] = sum_k A[m,k]*B[n,k] + bias[n]
// MODE 0: out = act(v) -> Yh f16; MODE 1: out = Yh + v (coalesced RMW)
// ACT: 0 none, 1 leaky, 2 relu ; SQ: atomicAdd row sum-of-squares of final f16 into Psq
template<int MODE, int ACT, bool SQ>
__global__ __launch_bounds__(512)
void mgemm(const _Float16* __restrict__ A, const _Float16* __restrict__ B,
           const float* __restrict__ bias, _Float16* __restrict__ Yh,
           float* __restrict__ Psq, int M, int K, int Nout)
{
    __shared__ _Float16 As[2][TBM * TBK];   // also reused as 128x128 f16 epilogue buffer
    __shared__ _Float16 Bs[2][TBN * TBK];
    const int tid = threadIdx.x;
    const int lane = tid & 63;
    const int wid = tid >> 6;               // 0..7
    const int wr = wid >> 1, wc = wid & 1;  // 4 x 2 wave grid

    int bid = xcd_swz(blockIdx.y * gridDim.x + blockIdx.x, gridDim.x * gridDim.y);
    const int m0 = (bid / gridDim.x) * TBM;
    const int n0 = (bid % gridDim.x) * TBN;

    f32x4 acc[4][4] = {};
    const int nt = K / TBK;

    const int lrow = lane >> 2;          // 0..15 row within chunk
    const int lk = (lane & 3) * 8;       // f16 offset within 32-elem k slab

    auto stage = [&](int t, int buf) {   // 3 gll per thread
        const int k0 = t * TBK;
#pragma unroll
        for (int q = 0; q < 2; q++) {
            int c = wid * 2 + q;                      // 0..15 (A chunks)
            int r = c * 16 + lrow;
            int am = min(m0 + r, M - 1);
            gll16(A + (size_t)am * K + k0 + lk, &As[buf][c * 512]);
        }
        {
            int c = wid;                              // 0..7 (B chunks)
            int r = c * 16 + lrow;
            int bn = min(n0 + r, Nout - 1);
            gll16(B + (size_t)bn * K + k0 + lk, &Bs[buf][c * 512]);
        }
    };

    stage(0, 0);
    __syncthreads();
    for (int t = 0; t < nt; ++t) {
        const int cur = t & 1;
        if (t + 1 < nt) stage(t + 1, cur ^ 1);
        f16x8 af[4], bf[4];
#pragma unroll
        for (int mi = 0; mi < 4; mi++)
            af[mi] = *(const f16x8*)(&As[cur][(wr * 64 + mi * 16 + (lane & 15)) * TBK + (lane >> 4) * 8]);
#pragma unroll
        for (int nj = 0; nj < 4; nj++)
            bf[nj] = *(const f16x8*)(&Bs[cur][(wc * 64 + nj * 16 + (lane & 15)) * TBK + (lane >> 4) * 8]);
#pragma unroll
        for (int mi = 0; mi < 4; mi++)
#pragma unroll
            for (int nj = 0; nj < 4; nj++)
                acc[mi][nj] = __builtin_amdgcn_mfma_f32_16x16x32_f16(af[mi], bf[nj], acc[mi][nj], 0, 0, 0);
        __syncthreads();
    }

    // ---- epilogue: repack 256x128 tile via LDS in two 128-row phases ----
    _Float16* eb = &As[0][0];            // 16384 f16 = 128 x 128
    const int g = lane >> 4;
#pragma unroll
    for (int p = 0; p < 2; p++) {
        if (p) __syncthreads();          // protect eb reuse between phases
        if ((wr >> 1) == p) {
#pragma unroll
            for (int nj = 0; nj < 4; nj++) {
                int col = wc * 64 + nj * 16 + (lane & 15);
                float bv = bias ? bias[n0 + col] : 0.f;
#pragma unroll
                for (int mi = 0; mi < 4; mi++)
#pragma unroll
                    for (int r = 0; r < 4; r++) {
                        int lr = (wr & 1) * 64 + mi * 16 + g * 4 + r;
                        float v = acc[mi][nj][r] + bv;
                        if (MODE == 0) {
                            if (ACT == 1) v = v > 0.f ? v : 0.01f * v;
                            else if (ACT == 2) v = fmaxf(v, 0.f);
                        }
                        eb[lr * 128 + col] = (_Float16)v;
                    }
            }
        }
        __syncthreads();
        // coalesced store: 512 threads x 4 consecutive octets (64B/thread)
        int t4 = tid * 4;
        int lr = t4 >> 4;                 // 0..127
        int cbase = (t4 & 15) * 8;        // 0,32,64,96
        int m = m0 + p * 128 + lr;
        float sq = 0.f;
        if (m < M) {
#pragma unroll
            for (int q = 0; q < 4; q++) {
                int c0 = cbase + q * 8;
                f16x8 hv = *(f16x8*)(eb + lr * 128 + c0);
                size_t gidx = (size_t)m * Nout + n0 + c0;
                if (MODE == 1) {
                    f16x8 old = *(f16x8*)(Yh + gidx);
                    f16x8 nw;
#pragma unroll
                    for (int e = 0; e < 8; e++) {
                        float s = (float)old[e] + (float)hv[e];
                        nw[e] = (_Float16)s;
                    }
                    *(f16x8*)(Yh + gidx) = nw;
                    hv = nw;
                } else {
                    *(f16x8*)(Yh + gidx) = hv;
                }
                if (SQ) {
#pragma unroll
                    for (int e = 0; e < 8; e++) { float f = (float)hv[e]; sq += f * f; }
                }
            }
        }
        if (SQ) {
            sq += __shfl_xor(sq, 1);
            sq += __shfl_xor(sq, 2);      // 4 threads per row share (lane&3)
            if ((lane & 3) == 0 && m < M) atomicAdd(&Psq[m], sq);
        }
    }
}

// ---------------- fused dual gate GEMM: 256x128 tile, 8 waves, repacked epilogue ----------------
__global__ __launch_bounds__(512)
void gatgemm(const _Float16* __restrict__ A, const _Float16* __restrict__ B1,
             const _Float16* __restrict__ B2, const float* __restrict__ c1,
             const float* __restrict__ c2, _Float16* __restrict__ Y,
             int M, int K, int Nout)
{
    __shared__ _Float16 As[2][TBM * TBK];
    __shared__ _Float16 B1s[2][TBN * TBK];
    __shared__ _Float16 B2s[2][TBN * TBK];
    const int tid = threadIdx.x;
    const int lane = tid & 63;
    const int wid = tid >> 6;
    const int wr = wid >> 1, wc = wid & 1;

    int bid = xcd_swz(blockIdx.y * gridDim.x + blockIdx.x, gridDim.x * gridDim.y);
    const int m0 = (bid / gridDim.x) * TBM;
    const int n0 = (bid % gridDim.x) * TBN;

    f32x4 acc1[4][4] = {};
    f32x4 acc2[4][4] = {};
    const int nt = K / TBK;

    const int lrow = lane >> 2;
    const int lk = (lane & 3) * 8;

    auto stage = [&](int t, int buf) {   // 4 gll per thread
        const int k0 = t * TBK;
#pragma unroll
        for (int q = 0; q < 2; q++) {
            int c = wid * 2 + q;
            int r = c * 16 + lrow;
            int am = min(m0 + r, M - 1);
            gll16(A + (size_t)am * K + k0 + lk, &As[buf][c * 512]);
        }
        {
            int c = wid;
            int r = c * 16 + lrow;
            int bn = min(n0 + r, Nout - 1);
            gll16(B1 + (size_t)bn * K + k0 + lk, &B1s[buf][c * 512]);
            gll16(B2 + (size_t)bn * K + k0 + lk, &B2s[buf][c * 512]);
        }
    };

    stage(0, 0);
    __syncthreads();
    for (int t = 0; t < nt; ++t) {
        const int cur = t & 1;
        if (t + 1 < nt) stage(t + 1, cur ^ 1);
        f16x8 af[4], bf1[4], bf2[4];
#pragma unroll
        for (int mi = 0; mi < 4; mi++)
            af[mi] = *(const f16x8*)(&As[cur][(wr * 64 + mi * 16 + (lane & 15)) * TBK + (lane >> 4) * 8]);
#pragma unroll
        for (int nj = 0; nj < 4; nj++) {
            int ro = (wc * 64 + nj * 16 + (lane & 15)) * TBK + (lane >> 4) * 8;
            bf1[nj] = *(const f16x8*)(&B1s[cur][ro]);
            bf2[nj] = *(const f16x8*)(&B2s[cur][ro]);
        }
#pragma unroll
        for (int mi = 0; mi < 4; mi++)
#pragma unroll
            for (int nj = 0; nj < 4; nj++) {
                acc1[mi][nj] = __builtin_amdgcn_mfma_f32_16x16x32_f16(af[mi], bf1[nj], acc1[mi][nj], 0, 0, 0);
                acc2[mi][nj] = __builtin_amdgcn_mfma_f32_16x16x32_f16(af[mi], bf2[nj], acc2[mi][nj], 0, 0, 0);
            }
        __syncthreads();
    }

    // ---- epilogue: gate + repack via LDS ----
    _Float16* eb = &As[0][0];
    const int g = lane >> 4;
#pragma unroll
    for (int p = 0; p < 2; p++) {
        if (p) __syncthreads();
        if ((wr >> 1) == p) {
#pragma unroll
            for (int nj = 0; nj < 4; nj++) {
                int col = wc * 64 + nj * 16 + (lane & 15);
                float bv1 = c1[n0 + col], bv2 = c2[n0 + col];
#pragma unroll
                for (int mi = 0; mi < 4; mi++)
#pragma unroll
                    for (int r = 0; r < 4; r++) {
                        int lr = (wr & 1) * 64 + mi * 16 + g * 4 + r;
                        float t1 = ftanh(acc1[mi][nj][r] + bv1);
                        float g1 = fsigmoid(acc2[mi][nj][r] + bv2);
                        eb[lr * 128 + col] = (_Float16)(t1 * g1);
                    }
            }
        }
        __syncthreads();
        int t4 = tid * 4;
        int lr = t4 >> 4;
        int cbase = (t4 & 15) * 8;
        int m = m0 + p * 128 + lr;
        if (m < M) {
#pragma unroll
            for (int q = 0; q < 4; q++) {
                int c0 = cbase + q * 8;
                f16x8 hv = *(f16x8*)(eb + lr * 128 + c0);
                *(f16x8*)(Y + (size_t)m * Nout + n0 + c0) = hv;
            }
        }
    }
}

// ---------------- fused sim GEMM + row softmax: 128-row blocks, 4 waves ----------------
// S = P@C^T ; sim = -sqrt(max(pp+cc-2S,1e-12))/denom ; Ah = softmax_row(sim) f16
#define SBM 128
__global__ __launch_bounds__(256)
void simgemm(const _Float16* __restrict__ A, const _Float16* __restrict__ B,
             const float* __restrict__ Psq, const float* __restrict__ Csq,
             const float* __restrict__ sscale, _Float16* __restrict__ Ah,
             int M, int K, int Kin)
{
    __shared__ _Float16 As[2][SBM * TBK];
    __shared__ _Float16 Bs[2][SBM * TBK];
    __shared__ float redmx[2][SBM];
    __shared__ float redsm[2][SBM];
    const int tid = threadIdx.x;
    const int lane = tid & 63;
    const int wid = tid >> 6;
    const int wr = wid >> 1, wc = wid & 1;
    const int m0 = blockIdx.y * SBM;

    f32x4 acc[4][4] = {};
    const int nt = K / TBK;
    const int lrow = lane >> 2;
    const int lk = (lane & 3) * 8;

    auto stage = [&](int t, int buf) {   // 4 gll per thread
        const int k0 = t * TBK;
#pragma unroll
        for (int q = 0; q < 2; q++) {
            int c = wid * 2 + q;          // 0..7
            int r = c * 16 + lrow;
            int am = min(m0 + r, M - 1);
            int bn = min(r, Kin - 1);
            gll16(A + (size_t)am * K + k0 + lk, &As[buf][c * 512]);
            gll16(B + (size_t)bn * K + k0 + lk, &Bs[buf][c * 512]);
        }
    };

    stage(0, 0);
    __syncthreads();
    for (int t = 0; t < nt; ++t) {
        const int cur = t & 1;
        if (t + 1 < nt) stage(t + 1, cur ^ 1);
        f16x8 af[4], bf[4];
#pragma unroll
        for (int mi = 0; mi < 4; mi++)
            af[mi] = *(const f16x8*)(&As[cur][(wr * 64 + mi * 16 + (lane & 15)) * TBK + (lane >> 4) * 8]);
#pragma unroll
        for (int nj = 0; nj < 4; nj++)
            bf[nj] = *(const f16x8*)(&Bs[cur][(wc * 64 + nj * 16 + (lane & 15)) * TBK + (lane >> 4) * 8]);
#pragma unroll
        for (int mi = 0; mi < 4; mi++)
#pragma unroll
            for (int nj = 0; nj < 4; nj++)
                acc[mi][nj] = __builtin_amdgcn_mfma_f32_16x16x32_f16(af[mi], bf[nj], acc[mi][nj], 0, 0, 0);
        __syncthreads();
    }

    const float denom = fmaxf(1e-6f, sscale[0]);
    const int colbase = wc * 64 + (lane & 15);
    const int g = lane >> 4;
    float cc[4];
#pragma unroll
    for (int nj = 0; nj < 4; nj++) {
        int n = colbase + nj * 16;
        cc[nj] = (n < Kin) ? Csq[n] : 0.f;
    }

    // pass 1: sim values into acc, per-row max -> LDS
#pragma unroll
    for (int mi = 0; mi < 4; mi++) {
#pragma unroll
        for (int r = 0; r < 4; r++) {
            int row = wr * 64 + mi * 16 + g * 4 + r;
            float pp = Psq[m0 + row];
            float mx = -INFINITY;
#pragma unroll
            for (int nj = 0; nj < 4; nj++) {
                int n = colbase + nj * 16;
                float v = -INFINITY;
                if (n < Kin)
                    v = -sqrtf(fmaxf(pp + cc[nj] - 2.f * acc[mi][nj][r], 1e-12f)) / denom;
                acc[mi][nj][r] = v;
                mx = fmaxf(mx, v);
            }
#pragma unroll
            for (int o = 1; o < 16; o <<= 1) mx = fmaxf(mx, __shfl_xor(mx, o));
            if ((lane & 15) == 0) redmx[wc][row] = mx;
        }
    }
    __syncthreads();

    // pass 2: exp + per-row sum -> LDS
#pragma unroll
    for (int mi = 0; mi < 4; mi++) {
#pragma unroll
        for (int r = 0; r < 4; r++) {
            int row = wr * 64 + mi * 16 + g * 4 + r;
            float mx = fmaxf(redmx[0][row], redmx[1][row]);
            float s = 0.f;
#pragma unroll
            for (int nj = 0; nj < 4; nj++) {
                int n = colbase + nj * 16;
                float e = (n < Kin) ? __expf(acc[mi][nj][r] - mx) : 0.f;
                acc[mi][nj][r] = e;
                s += e;
            }
#pragma unroll
            for (int o = 1; o < 16; o <<= 1) s += __shfl_xor(s, o);
            if ((lane & 15) == 0) redsm[wc][row] = s;
        }
    }
    __syncthreads();

    // pass 3: normalize + write f16
#pragma unroll
    for (int mi = 0; mi < 4; mi++) {
#pragma unroll
        for (int r = 0; r < 4; r++) {
            int row = wr * 64 + mi * 16 + g * 4 + r;
            float inv = __builtin_amdgcn_rcpf(redsm[0][row] + redsm[1][row]);
            int m = m0 + row;
#pragma unroll
            for (int nj = 0; nj < 4; nj++) {
                int n = colbase + nj * 16;
                if (n < Kin)
                    Ah[(size_t)m * Kin + n] = (_Float16)(acc[mi][nj][r] * inv);
            }
        }
    }
}

// ---------------- converters ----------------
__global__ __launch_bounds__(256)
void cvt_k(const float* __restrict__ x, _Float16* __restrict__ y, int n)
{
    int i = (blockIdx.x * 256 + threadIdx.x) * 4;
    if (i < n) {
        float4 v = *(const float4*)(x + i);
        f16x4 h = { (_Float16)v.x, (_Float16)v.y, (_Float16)v.z, (_Float16)v.w };
        *(f16x4*)(y + i) = h;
    }
}

// C [Kin,512] fp32 -> Ch, CTh f16 + Csq row sum-of-squares; one wave per row
__global__ __launch_bounds__(256)
void cvtC2_k(const float* __restrict__ C, _Float16* __restrict__ Ch,
             _Float16* __restrict__ CTh, float* __restrict__ Csq, int Kin)
{
    int w = threadIdx.x >> 6, lane = threadIdx.x & 63;
    int row = blockIdx.x * 4 + w;
    if (row >= Kin) return;
    float4 a = *(const float4*)(C + (size_t)row * 512 + lane * 8);
    float4 b = *(const float4*)(C + (size_t)row * 512 + lane * 8 + 4);
    f16x8 h;
    h[0] = (_Float16)a.x; h[1] = (_Float16)a.y; h[2] = (_Float16)a.z; h[3] = (_Float16)a.w;
    h[4] = (_Float16)b.x; h[5] = (_Float16)b.y; h[6] = (_Float16)b.z; h[7] = (_Float16)b.w;
    *(f16x8*)(Ch + (size_t)row * 512 + lane * 8) = h;
    float s = 0.f;
#pragma unroll
    for (int q = 0; q < 8; q++) {
        float f = (float)h[q];
        s += f * f;
        CTh[(size_t)(lane * 8 + q) * Kin + row] = h[q];
    }
#pragma unroll
    for (int o = 32; o; o >>= 1) s += __shfl_xor(s, o);
    if (lane == 0) Csq[row] = s;
}

// ---------------- small kernels (f16 activations) ----------------
// Yh = LN(X (+R)) * g + b, f16 in/out, fp32 math; one wave per row
__global__ __launch_bounds__(256)
void ln_k(const _Float16* __restrict__ X, const _Float16* __restrict__ R,
          const float* __restrict__ g, const float* __restrict__ b,
          _Float16* __restrict__ Yh, int M)
{
    int wid = threadIdx.x >> 6, lane = threadIdx.x & 63;
    int row = blockIdx.x * 4 + wid;
    if (row >= M) return;
    f16x8 a = *(const f16x8*)(X + (size_t)row * 512 + lane * 8);
    float v[8];
#pragma unroll
    for (int q = 0; q < 8; q++) v[q] = (float)a[q];
    if (R) {
        f16x8 c = *(const f16x8*)(R + (size_t)row * 512 + lane * 8);
#pragma unroll
        for (int q = 0; q < 8; q++) v[q] += (float)c[q];
    }
    float s = 0.f, ss = 0.f;
#pragma unroll
    for (int q = 0; q < 8; q++) { s += v[q]; ss += v[q] * v[q]; }
#pragma unroll
    for (int o = 32; o; o >>= 1) { s += __shfl_xor(s, o); ss += __shfl_xor(ss, o); }
    float mean = s * (1.f / 512.f);
    float var = ss * (1.f / 512.f) - mean * mean;
    float inv = 1.f / sqrtf(var + 1e-5f);
    int d0 = lane * 8;
    f16x8 o8;
#pragma unroll
    for (int q = 0; q < 8; q++)
        o8[q] = (_Float16)((v[q] - mean) * inv * g[d0 + q] + b[d0 + q]);
    *(f16x8*)(Yh + (size_t)row * 512 + d0) = o8;
}

__global__ __launch_bounds__(256)
void red1_k(const float* __restrict__ C, const float* __restrict__ w1,
            const float* __restrict__ b1, float* __restrict__ H1, int Kin)
{
    int d = blockIdx.x * 256 + threadIdx.x;
    int j = blockIdx.y;
    float acc = b1[j];
    for (int k = 0; k < Kin; k++) acc = fmaf(C[(size_t)k * 512 + d], w1[(size_t)j * Kin + k], acc);
    H1[(size_t)j * 512 + d] = fmaxf(acc, 0.f);
}

__global__ __launch_bounds__(256)
void red2_k(const float* __restrict__ H1, const float* __restrict__ w2,
            const float* __restrict__ b2, float* __restrict__ Cn, int Kin, int Kout)
{
    int d = blockIdx.x * 256 + threadIdx.x;
    int j2 = blockIdx.y;
    float acc = b2[j2];
    for (int j = 0; j < Kin; j++) acc = fmaf(H1[(size_t)j * 512 + d], w2[(size_t)j2 * Kin + j], acc);
    Cn[(size_t)j2 * 512 + d] = acc;
}

// scores[i] = dot(TG[i,:], Ws) + bs; TG f16
__global__ __launch_bounds__(256)
void score_k(const _Float16* __restrict__ TG, const float* __restrict__ Ws,
             const float* __restrict__ bs, float* __restrict__ out, int M)
{
    int wid = threadIdx.x >> 6, lane = threadIdx.x & 63;
    int row = blockIdx.x * 4 + wid;
    if (row >= M) return;
    f16x8 a = *(const f16x8*)(TG + (size_t)row * 512 + lane * 8);
    float4 w0 = *(const float4*)(Ws + lane * 8);
    float4 w1 = *(const float4*)(Ws + lane * 8 + 4);
    float d = (float)a[0] * w0.x + (float)a[1] * w0.y + (float)a[2] * w0.z + (float)a[3] * w0.w
            + (float)a[4] * w1.x + (float)a[5] * w1.y + (float)a[6] * w1.z + (float)a[7] * w1.w;
#pragma unroll
    for (int o = 32; o; o >>= 1) d += __shfl_xor(d, o);
    if (lane == 0) out[row] = d + bs[0];
}

__global__ __launch_bounds__(1024)
void pool_k(float* __restrict__ s, float* __restrict__ scal, int M)
{
    __shared__ float sm[16];
    int tid = threadIdx.x, lane = tid & 63, wid = tid >> 6;
    float mx = -INFINITY;
    for (int i = tid * 4; i < M; i += 4096) {
        float4 a = *(const float4*)(s + i);
        mx = fmaxf(fmaxf(fmaxf(mx, a.x), fmaxf(a.y, a.z)), a.w);
    }
#pragma unroll
    for (int o = 32; o; o >>= 1) mx = fmaxf(mx, __shfl_xor(mx, o));
    if (lane == 0) sm[wid] = mx;
    __syncthreads();
    if (wid == 0) {
        float v = (lane < 16) ? sm[lane] : -INFINITY;
#pragma unroll
        for (int o = 8; o; o >>= 1) v = fmaxf(v, __shfl_xor(v, o));
        if (lane == 0) sm[0] = v;
    }
    __syncthreads();
    float gmax = sm[0];
    __syncthreads();
    float sum = 0.f;
    for (int i = tid * 4; i < M; i += 4096) {
        float4 a = *(const float4*)(s + i);
        float4 e;
        e.x = __expf(a.x - gmax); e.y = __expf(a.y - gmax);
        e.z = __expf(a.z - gmax); e.w = __expf(a.w - gmax);
        *(float4*)(s + i) = e;
        sum += e.x + e.y + e.z + e.w;
    }
#pragma unroll
    for (int o = 32; o; o >>= 1) sum += __shfl_xor(sum, o);
    if (lane == 0) sm[wid] = sum;
    __syncthreads();
    if (tid == 0) {
        float t = 0.f;
        for (int w = 0; w < 16; w++) t += sm[w];
        scal[0] = t;
    }
}

__global__ __launch_bounds__(256)
void bagp_k(const _Float16* __restrict__ Z, const float* __restrict__ w,
            float* __restrict__ PB, int M, int cs)
{
    int d = blockIdx.x * 256 + threadIdx.x;
    int chunk = blockIdx.y;
    int i0 = chunk * cs;
    int i1 = min(M, i0 + cs);
    float acc = 0.f;
    for (int i = i0; i < i1; i++) acc = fmaf(w[i], (float)Z[(size_t)i * 512 + d], acc);
    PB[(size_t)chunk * 512 + d] = acc;
}

__global__ __launch_bounds__(256)
void bagf_k(const float* __restrict__ PB, const float* __restrict__ scal,
            float* __restrict__ bag, int nchunk)
{
    int d = blockIdx.x * 256 + threadIdx.x;
    float acc = 0.f;
    for (int c = 0; c < nchunk; c++) acc += PB[(size_t)c * 512 + d];
    bag[d] = acc / scal[0];
}

__global__ __launch_bounds__(256)
void h_k(const float* __restrict__ bag, const float* __restrict__ Wh,
         const float* __restrict__ bh, float* __restrict__ h)
{
    int wid = threadIdx.x >> 6, lane = threadIdx.x & 63;
    int j = blockIdx.x * 4 + wid;
    const float* wr = Wh + (size_t)j * 512;
    float d = 0.f;
#pragma unroll
    for (int t = 0; t < 2; t++) {
        float4 a = *(const float4*)(wr + t * 256 + lane * 4);
        float4 bv = *(const float4*)(bag + t * 256 + lane * 4);
        d += a.x * bv.x + a.y * bv.y + a.z * bv.z + a.w * bv.w;
    }
#pragma unroll
    for (int o = 32; o; o >>= 1) d += __shfl_xor(d, o);
    if (lane == 0) h[j] = fmaxf(d + bh[j], 0.f);
}

__global__ __launch_bounds__(128)
void logit_k(const float* __restrict__ h, const float* __restrict__ Wc,
             const float* __restrict__ bc, float* __restrict__ out)
{
    int wid = threadIdx.x >> 6, lane = threadIdx.x & 63;
    const float* wr = Wc + (size_t)wid * 512;
    float d = 0.f;
#pragma unroll
    for (int t = 0; t < 2; t++) {
        float4 a = *(const float4*)(wr + t * 256 + lane * 4);
        float4 hv = *(const float4*)(h + t * 256 + lane * 4);
        d += a.x * hv.x + a.y * hv.y + a.z * hv.z + a.w * hv.w;
    }
#pragma unroll
    for (int o = 32; o; o >>= 1) d += __shfl_xor(d, o);
    if (lane == 0) out[wid] = d + bc[wid];
}

extern "C" void kernel_launch(void* const* d_in, const int* in_sizes, int n_in,
                              void* d_out, int out_size, void* d_ws, size_t ws_size,
                              hipStream_t stream)
{
    const float* data    = (const float*)d_in[0];
    const float* protos  = (const float*)d_in[1];
    const float* W_pp    = (const float*)d_in[2];
    const float* b_pp    = (const float*)d_in[3];
    const float* W_cp    = (const float*)d_in[4];
    const float* b_cp    = (const float*)d_in[5];
    const float* sscale  = (const float*)d_in[6];
    const float* enh_w1  = (const float*)d_in[7];
    const float* enh_b1  = (const float*)d_in[8];
    const float* enh_w2  = (const float*)d_in[9];
    const float* enh_b2  = (const float*)d_in[10];
    const float* ln_g    = (const float*)d_in[11];
    const float* ln_b    = (const float*)d_in[12];
    const float* red_w1[3] = {(const float*)d_in[13], (const float*)d_in[17], (const float*)d_in[21]};
    const float* red_b1[3] = {(const float*)d_in[14], (const float*)d_in[18], (const float*)d_in[22]};
    const float* red_w2[3] = {(const float*)d_in[15], (const float*)d_in[19], (const float*)d_in[23]};
    const float* red_b2[3] = {(const float*)d_in[16], (const float*)d_in[20], (const float*)d_in[24]};
    const float* W_proc  = (const float*)d_in[25];
    const float* b_proc  = (const float*)d_in[26];
    const float* g_an    = (const float*)d_in[27];
    const float* b_an    = (const float*)d_in[28];
    const float* W_t     = (const float*)d_in[29];
    const float* b_t     = (const float*)d_in[30];
    const float* W_g     = (const float*)d_in[31];
    const float* b_g     = (const float*)d_in[32];
    const float* W_s     = (const float*)d_in[33];
    const float* b_s     = (const float*)d_in[34];
    const float* W_h     = (const float*)d_in[35];
    const float* b_h     = (const float*)d_in[36];
    const float* W_c     = (const float*)d_in[37];
    const float* b_c     = (const float*)d_in[38];
    float* out = (float*)d_out;

    constexpr int N = 32768, DIN = 768, D = 512;
    constexpr int NCHUNK = 256;
    char* w = (char*)d_ws;
    auto alloc = [&](size_t bytes) -> char* {
        char* p = w; w += (bytes + 255) & ~(size_t)255; return p;
    };
    _Float16* Ph     = (_Float16*)alloc((size_t)N * D * 2);
    _Float16* CTXh   = (_Float16*)alloc((size_t)N * D * 2);
    _Float16* TMPh   = (_Float16*)alloc((size_t)N * D * 2);
    _Float16* Zrawh  = (_Float16*)alloc((size_t)(N + 16) * D * 2);
    _Float16* Zh     = (_Float16*)alloc((size_t)(N + 16) * D * 2);
    _Float16* TGh    = (_Float16*)alloc((size_t)(N + 16) * D * 2);
    _Float16* datah  = (_Float16*)alloc((size_t)N * DIN * 2);
    _Float16* Ah     = (_Float16*)alloc((size_t)N * 128 * 2);
    _Float16* Ch     = (_Float16*)alloc(128 * D * 2);
    _Float16* CTh    = (_Float16*)alloc(128 * D * 2);
    _Float16* Wpph   = (_Float16*)alloc((size_t)D * DIN * 2);
    _Float16* w1h    = (_Float16*)alloc((size_t)3 * D * D * 2);
    _Float16* w2h    = (_Float16*)alloc((size_t)3 * D * D * 2);
    _Float16* Wproch = (_Float16*)alloc((size_t)D * D * 2);
    _Float16* Wth    = (_Float16*)alloc((size_t)D * D * 2);
    _Float16* Wgh    = (_Float16*)alloc((size_t)D * D * 2);
    float*    Psq    = (float*)alloc((size_t)N * 4);
    float*    Csq    = (float*)alloc(128 * 4);
    float*    Ca     = (float*)alloc(128 * D * 4);
    float*    Cb     = (float*)alloc(128 * D * 4);
    float*    H1     = (float*)alloc(128 * D * 4);
    float*    scr    = (float*)alloc((size_t)(N + 16) * 4);
    float*    PB     = (float*)alloc((size_t)NCHUNK * D * 4);
    float*    bag    = (float*)alloc(D * 4);
    float*    hb     = (float*)alloc(D * 4);
    float*    scal   = (float*)alloc(8 * 4);

    dim3 blk(256);
    dim3 blk512(512);
    auto cgrid = [](size_t n) { return dim3((unsigned)((n / 4 + 255) / 256)); };
    auto mgrid = [](int M_, int Nout_) { return dim3((Nout_ + TBN - 1) / TBN, (M_ + TBM - 1) / TBM); };

    // --- convert weights + data to f16 ---
    cvt_k<<<cgrid((size_t)N * DIN), blk, 0, stream>>>(data, datah, N * DIN);
    cvt_k<<<cgrid((size_t)D * DIN), blk, 0, stream>>>(W_pp, Wpph, D * DIN);
    cvt_k<<<cgrid((size_t)3 * D * D), blk, 0, stream>>>(enh_w1, w1h, 3 * D * D);
    cvt_k<<<cgrid((size_t)3 * D * D), blk, 0, stream>>>(enh_w2, w2h, 3 * D * D);
    cvt_k<<<cgrid((size_t)D * D), blk, 0, stream>>>(W_proc, Wproch, D * D);
    cvt_k<<<cgrid((size_t)D * D), blk, 0, stream>>>(W_t, Wth, D * D);
    cvt_k<<<cgrid((size_t)D * D), blk, 0, stream>>>(W_g, Wgh, D * D);

    // P = leaky(data @ W_pp^T + b_pp) -> f16, with fused Psq accumulation
    hipMemsetAsync(Psq, 0, (size_t)N * 4, stream);
    mgemm<0, 1, true><<<mgrid(N, D), blk512, 0, stream>>>(datah, Wpph, b_pp, Ph, Psq, N, DIN, D);
    // C0 = leaky(protos @ W_cp^T + b_cp) -> fp32 (tiny)
    dot_k<1, false><<<dim3(128 * 512 / 4), blk, 0, stream>>>(protos, W_cp, b_cp, Ca, 128, DIN);

    float* C = Ca;
    float* Cn = Cb;
    int Kin = 128;
    for (int i = 0; i < 3; i++) {
        int Kout = Kin >> 1;
        cvtC2_k<<<dim3((Kin + 3) / 4), blk, 0, stream>>>(C, Ch, CTh, Csq, Kin);
        // A = softmax(-dist/denom) fused with S = P@C^T
        simgemm<<<dim3(1, N / SBM), blk, 0, stream>>>(Ph, Ch, Psq, Csq, sscale, Ah, N, D, Kin);
        if (i < 2) hipMemsetAsync(Psq, 0, (size_t)N * 4, stream);   // ready for next iter's enh2
        // ctx = A @ C -> f16
        mgemm<0, 0, false><<<mgrid(N, D), blk512, 0, stream>>>(Ah, CTh, nullptr, CTXh, nullptr, N, Kin, D);
        // P = LN(P + ctx) -> f16
        ln_k<<<dim3((N + 3) / 4), blk, 0, stream>>>(Ph, CTXh, ln_g + (size_t)i * D, ln_b + (size_t)i * D, Ph, N);
        // enhancer MLP: P += w2 @ relu(w1 @ P + b1) + b2   (enh2 fuses Psq for next iter)
        mgemm<0, 2, false><<<mgrid(N, D), blk512, 0, stream>>>(Ph, w1h + (size_t)i * D * D, enh_b1 + (size_t)i * D, TMPh, nullptr, N, D, D);
        if (i < 2)
            mgemm<1, 0, true><<<mgrid(N, D), blk512, 0, stream>>>(TMPh, w2h + (size_t)i * D * D, enh_b2 + (size_t)i * D, Ph, Psq, N, D, D);
        else
            mgemm<1, 0, false><<<mgrid(N, D), blk512, 0, stream>>>(TMPh, w2h + (size_t)i * D * D, enh_b2 + (size_t)i * D, Ph, nullptr, N, D, D);
        // ProtoReducer (fp32, tiny)
        red1_k<<<dim3(2, Kin), blk, 0, stream>>>(C, red_w1[i], red_b1[i], H1, Kin);
        red2_k<<<dim3(2, Kout), blk, 0, stream>>>(H1, red_w2[i], red_b2[i], Cn, Kin, Kout);
        float* t = C; C = Cn; Cn = t;
        Kin = Kout;
    }

    // Zraw = relu(proc([P; C]))
    mgemm<0, 2, false><<<mgrid(N, D), blk512, 0, stream>>>(Ph, Wproch, b_proc, Zrawh, nullptr, N, D, D);
    dot_k<2, true><<<dim3(16 * 512 / 4), blk, 0, stream>>>(C, W_proc, b_proc, Zrawh + (size_t)N * D, 16, D);
    // Z = LN(Zraw)
    ln_k<<<dim3((N + 16 + 3) / 4), blk, 0, stream>>>(Zrawh, nullptr, g_an, b_an, Zh, N + 16);

    // TG = tanh(Z@W_t^T+b_t) * sigmoid(Z@W_g^T+b_g)  (fused dual GEMM)
    gatgemm<<<mgrid(N + 16, D), blk512, 0, stream>>>(Zh, Wth, Wgh, b_t, b_g, TGh, N + 16, D, D);

    // attention pooling
    score_k<<<dim3((N + 16 + 3) / 4), blk, 0, stream>>>(TGh, W_s, b_s, scr, N + 16);
    pool_k<<<dim3(1), dim3(1024), 0, stream>>>(scr, scal, N + 16);
    int cs = (N + 16 + NCHUNK - 1) / NCHUNK;
    bagp_k<<<dim3(2, NCHUNK), blk, 0, stream>>>(Zh, scr, PB, N + 16, cs);
    bagf_k<<<dim3(2), blk, 0, stream>>>(PB, scal, bag, NCHUNK);

    // classifier head
    h_k<<<dim3(128), blk, 0, stream>>>(bag, W_h, b_h, hb);
    logit_k<<<dim3(1), dim3(128), 0, stream>>>(hb, W_c, b_c, out);
}